// Round 5
// baseline (4349.162 us; speedup 1.0000x reference)
//
#include <hip/hip_runtime.h>
#include <hip/hip_bf16.h>
#include <hip/hip_cooperative_groups.h>

namespace cg = cooperative_groups;

#define TPB 256
constexpr int B_ = 256, S_ = 512, D_ = 512, Q_ = 256, NM_ = 512;
constexpr int NB = 64, NT = 8;

typedef _Float16 f16x8 __attribute__((ext_vector_type(8)));
typedef float f32x4 __attribute__((ext_vector_type(4)));

// XCD-co-locating decode: x=bid&7 -> XCD; per XCD: tiles fastest, then cls, then group.
__device__ __forceinline__ void decode_mt(int bid, int W, int& m, int& t){
  int x = bid & 7, r = bid >> 3;
  t = r % W; int u = r / W;
  m = (((u >> 1)*8 + x) << 1) | (u & 1);
}
__device__ __forceinline__ int mkm(int xcd, int u){
  return (((u >> 1)*8 + xcd) << 1) | (u & 1);
}

// direct row-major 64x64 stage into pitch-68 LDS (256 threads)
__device__ __forceinline__ void stage_D(const float* __restrict__ src, size_t ld,
                                        float (*dst)[68], int t)
{
  int r = t >> 2, seg = (t & 3) * 16;
  const float4* s4 = (const float4*)(src + (size_t)r*ld + seg);
  #pragma unroll
  for (int i=0;i<4;i++) *((float4*)&dst[r][seg + i*4]) = s4[i];
}
__device__ __forceinline__ void stage68c(const float* __restrict__ src, size_t ld,
                                         float* __restrict__ dst, int t)
{
  int r = t >> 2, seg = (t & 3) * 16;
  const float4* s4 = (const float4*)(src + (size_t)r*ld + seg);
  #pragma unroll
  for (int i=0;i<4;i++) *((float4*)&dst[r*68 + seg + i*4]) = s4[i];
}

// transposed stage: dst[col][row] = src[row][col]
__device__ __forceinline__ void stage_T(const float* __restrict__ src, size_t ld,
                                        float (*dst)[68], int t)
{
  int r = t >> 2, seg = (t & 3) * 16;
  const float4* s4 = (const float4*)(src + (size_t)r*ld + seg);
  #pragma unroll
  for (int i=0;i<4;i++){
    float4 v = s4[i];
    dst[seg + i*4 + 0][r] = v.x;
    dst[seg + i*4 + 1][r] = v.y;
    dst[seg + i*4 + 2][r] = v.z;
    dst[seg + i*4 + 3][r] = v.w;
  }
}

// ---------------- stats: counts, means, pos bitmask ----------------
__global__ __launch_bounds__(TPB) void k_stats(const float* __restrict__ X,
                                               const int* __restrict__ labels,
                                               const int* __restrict__ slen,
                                               float* __restrict__ mu,
                                               float* __restrict__ cnt,
                                               unsigned int* __restrict__ wpbits)
{
  int b = blockIdx.x, t = threadIdx.x;
  __shared__ int lab[S_];
  __shared__ float red[TPB];
  int L = slen[b];
  for (int s = t; s < S_; s += TPB) {
    int lb = labels[b*S_ + s];
    lab[s] = (s < L) ? lb : -1;
  }
  __syncthreads();
  if (t < 16) {
    unsigned int wword = 0;
    for (int i2 = 0; i2 < 32; i2++) if (lab[t*32 + i2] == 1) wword |= (1u << i2);
    wpbits[b*16 + t] = wword;
  }
  int cpi=0, cni=0;
  for (int s=t; s<S_; s+=TPB){ cpi += (lab[s]==1); cni += (lab[s]==0); }
  red[t] = (float)cpi; __syncthreads();
  for (int o=TPB/2;o>0;o>>=1){ if(t<o) red[t]+=red[t+o]; __syncthreads(); }
  float cp = red[0]; __syncthreads();
  red[t] = (float)cni; __syncthreads();
  for (int o=TPB/2;o>0;o>>=1){ if(t<o) red[t]+=red[t+o]; __syncthreads(); }
  float cn = red[0];
  if (t==0){ cnt[b*2+0]=cn; cnt[b*2+1]=cp; }
  float sp0=0,sp1=0,sn0=0,sn1=0;
  const float* Xb = X + (size_t)b*S_*D_;
  for (int s=0;s<S_;s++){
    int e = lab[s];
    if (e < 0) continue;
    float x0 = Xb[(size_t)s*D_ + t];
    float x1 = Xb[(size_t)s*D_ + t + 256];
    if (e==1){ sp0+=x0; sp1+=x1; } else { sn0+=x0; sn1+=x1; }
  }
  float stv = (float)L;
  float* mb = mu + (size_t)b*3*D_;
  mb[0*D_ + t] = sn0/cn;        mb[0*D_ + t+256] = sn1/cn;
  mb[1*D_ + t] = sp0/cp;        mb[1*D_ + t+256] = sp1/cp;
  mb[2*D_ + t] = (sn0+sp0)/stv; mb[2*D_ + t+256] = (sn1+sp1)/stv;
}

// ---------------- prep: transpose X -> f16 hi/lo [B][D][S], valid-masked ----------------
__global__ __launch_bounds__(TPB) void k_prep(const float* __restrict__ X,
                                              const int* __restrict__ slen,
                                              unsigned short* __restrict__ Xvh,
                                              unsigned short* __restrict__ Xvl)
{
  int b = blockIdx.y, z = blockIdx.x;
  int d0 = (z>>3)*64, s0 = (z&7)*64;
  int t = threadIdx.x;
  __shared__ float Tl[64][65];
  const float* src = X + ((size_t)b*S_ + s0)*D_ + d0;
  { int r = t>>2, seg = (t&3)*16;
    const float4* s4 = (const float4*)(src + (size_t)r*D_ + seg);
    #pragma unroll
    for (int i=0;i<4;i++){ float4 v = s4[i];
      Tl[seg+i*4+0][r]=v.x; Tl[seg+i*4+1][r]=v.y; Tl[seg+i*4+2][r]=v.z; Tl[seg+i*4+3][r]=v.w; } }
  __syncthreads();
  int L = slen[b];
  int dr = t>>2, sc = (t&3)*16;
  union U16 { unsigned short u[8]; uint4 v; };
  U16 H[2], Lo[2];
  #pragma unroll
  for (int g=0; g<2; g++)
    #pragma unroll
    for (int i=0;i<8;i++){
      int si = sc + g*8 + i;
      float x = (s0+si < L) ? Tl[dr][si] : 0.f;
      _Float16 hh = (_Float16)x;
      float lo = x - (float)hh;
      H[g].u[i]  = __builtin_bit_cast(unsigned short, hh);
      Lo[g].u[i] = __builtin_bit_cast(unsigned short, (_Float16)lo);
    }
  size_t o = ((size_t)b*D_ + d0+dr)*S_ + s0 + sc;
  *(uint4*)(Xvh+o)   = H[0].v;  *(uint4*)(Xvh+o+8) = H[1].v;
  *(uint4*)(Xvl+o)   = Lo[0].v; *(uint4*)(Xvl+o+8) = Lo[1].v;
}

// ---------------- MFMA Gram -> A matrices (upper 128-tiles incl. diagonal) ----------------
__global__ __launch_bounds__(TPB,2) void k_gram(const unsigned short* __restrict__ Xvh,
                                                const unsigned short* __restrict__ Xvl,
                                                const unsigned int* __restrict__ wpbits,
                                                const float* __restrict__ mu,
                                                const float* __restrict__ cnt,
                                                const int* __restrict__ slen,
                                                float* __restrict__ A)
{
  __shared__ unsigned short sAvh[128][32], sAvl[128][32], sAph[128][32], sApl[128][32],
                            sBvh[128][32], sBvl[128][32];
  int id = blockIdx.x;
  int g = id>>3;
  int b = (g/10)*8 + (id&7);
  int z = g%10;
  int ti=0; while (z >= 4-ti){ z -= 4-ti; ti++; } int tj = ti + z;
  int i0 = ti*128, j0 = tj*128;
  int t = threadIdx.x, lane = t&63, w = t>>6;
  int wr = w>>1, wc = w&1, l15 = lane&15;

  f32x4 acc_t[4][4], acc_p[4][4];
  f32x4 z4 = {0.f,0.f,0.f,0.f};
  #pragma unroll
  for (int mf=0;mf<4;mf++)
    #pragma unroll
    for (int nf=0;nf<4;nf++){ acc_t[mf][nf]=z4; acc_p[mf][nf]=z4; }

  const size_t baseA = ((size_t)b*D_ + i0)*S_;
  const size_t baseB = ((size_t)b*D_ + j0)*S_;
  int phx = (lane>>4) ^ ((l15>>1)&3);

  for (int ks=0; ks<16; ks++){
    int s0 = ks*32;
    unsigned int wpw = wpbits[b*16 + ks];
    __syncthreads();
    #pragma unroll
    for (int h=0; h<2; h++){
      int ci = t + h*256;
      int row = ci>>2, cpos = ci&3;
      int ph = cpos ^ ((row>>1)&3);
      size_t ga = baseA + (size_t)row*S_ + s0 + cpos*8;
      size_t gb = baseB + (size_t)row*S_ + s0 + cpos*8;
      uint4 vh = *(const uint4*)(Xvh+ga);
      uint4 vl = *(const uint4*)(Xvl+ga);
      uint4 bh = *(const uint4*)(Xvh+gb);
      uint4 bl = *(const uint4*)(Xvl+gb);
      unsigned int m8 = (wpw >> (cpos*8)) & 0xFFu;
      uint4 mk;
      mk.x = ((m8&1u)?0xFFFFu:0u)  | ((m8&2u)?0xFFFF0000u:0u);
      mk.y = ((m8&4u)?0xFFFFu:0u)  | ((m8&8u)?0xFFFF0000u:0u);
      mk.z = ((m8&16u)?0xFFFFu:0u) | ((m8&32u)?0xFFFF0000u:0u);
      mk.w = ((m8&64u)?0xFFFFu:0u) | ((m8&128u)?0xFFFF0000u:0u);
      uint4 p4, q4;
      p4.x = vh.x&mk.x; p4.y = vh.y&mk.y; p4.z = vh.z&mk.z; p4.w = vh.w&mk.w;
      q4.x = vl.x&mk.x; q4.y = vl.y&mk.y; q4.z = vl.z&mk.z; q4.w = vl.w&mk.w;
      *(uint4*)&sAvh[row][ph*8] = vh;
      *(uint4*)&sAvl[row][ph*8] = vl;
      *(uint4*)&sAph[row][ph*8] = p4;
      *(uint4*)&sApl[row][ph*8] = q4;
      *(uint4*)&sBvh[row][ph*8] = bh;
      *(uint4*)&sBvl[row][ph*8] = bl;
    }
    __syncthreads();
    f16x8 Avh[4], Avl[4], Aph[4], Apl[4];
    #pragma unroll
    for (int mf=0;mf<4;mf++){
      int r = wr*64 + mf*16 + l15;
      Avh[mf] = __builtin_bit_cast(f16x8, *(const uint4*)&sAvh[r][phx*8]);
      Avl[mf] = __builtin_bit_cast(f16x8, *(const uint4*)&sAvl[r][phx*8]);
      Aph[mf] = __builtin_bit_cast(f16x8, *(const uint4*)&sAph[r][phx*8]);
      Apl[mf] = __builtin_bit_cast(f16x8, *(const uint4*)&sApl[r][phx*8]);
    }
    #pragma unroll
    for (int nf=0;nf<4;nf++){
      int r = wc*64 + nf*16 + l15;
      f16x8 Bh = __builtin_bit_cast(f16x8, *(const uint4*)&sBvh[r][phx*8]);
      f16x8 Bl = __builtin_bit_cast(f16x8, *(const uint4*)&sBvl[r][phx*8]);
      #pragma unroll
      for (int mf=0;mf<4;mf++){
        acc_t[mf][nf] = __builtin_amdgcn_mfma_f32_16x16x32_f16(Avh[mf], Bh, acc_t[mf][nf],0,0,0);
        acc_t[mf][nf] = __builtin_amdgcn_mfma_f32_16x16x32_f16(Avh[mf], Bl, acc_t[mf][nf],0,0,0);
        acc_t[mf][nf] = __builtin_amdgcn_mfma_f32_16x16x32_f16(Avl[mf], Bh, acc_t[mf][nf],0,0,0);
        acc_p[mf][nf] = __builtin_amdgcn_mfma_f32_16x16x32_f16(Aph[mf], Bh, acc_p[mf][nf],0,0,0);
        acc_p[mf][nf] = __builtin_amdgcn_mfma_f32_16x16x32_f16(Aph[mf], Bl, acc_p[mf][nf],0,0,0);
        acc_p[mf][nf] = __builtin_amdgcn_mfma_f32_16x16x32_f16(Apl[mf], Bh, acc_p[mf][nf],0,0,0);
      }
    }
  }
  float cn = cnt[b*2+0], cp = cnt[b*2+1];
  float stv = (float)slen[b];
  float kn = 0.1f/(cn-1.f), kp = 0.1f/(cp-1.f), kt = 0.9f/(stv-1.f);
  float rn = 0.1f*cn/(cn-1.f), rp = 0.1f*cp/(cp-1.f), rt = 0.9f*stv/(stv-1.f);
  const float* mb = mu + (size_t)b*3*D_;
  float* A0 = A + (size_t)(b*2+0)*D_*D_;
  float* A1 = A + (size_t)(b*2+1)*D_*D_;
  int rbase = i0 + wr*64 + (lane>>4)*4;
  int cbase = j0 + wc*64 + l15;
  #pragma unroll
  for (int mf=0;mf<4;mf++){
    #pragma unroll
    for (int i=0;i<4;i++){
      int r = rbase + mf*16 + i;
      float mnr = mb[r], mpr = mb[D_+r], mtr = mb[2*D_+r];
      #pragma unroll
      for (int nf=0;nf<4;nf++){
        int c = cbase + nf*16;
        float mnc = mb[c], mpc = mb[D_+c], mtc = mb[2*D_+c];
        float gp = acc_p[mf][nf][i];
        float gt = acc_t[mf][nf][i];
        float gn = gt - gp;
        float diag = (r==c)?0.1f:0.f;
        A0[(size_t)r*D_ + c] = kn*gn + kt*gt - rn*mnr*mnc - rt*mtr*mtc + diag;
        A1[(size_t)r*D_ + c] = kp*gp + kt*gt - rp*mpr*mpc - rt*mtr*mtc + diag;
      }
    }
  }
}

// ================= cooperative fused Cholesky bodies =================

// trail pair (a,b): C -= Pa^T Pb  (RMW global)
__device__ __forceinline__ void body_trail(const float* __restrict__ Pa,
                                           const float* __restrict__ Pb,
                                           float* __restrict__ Cb,
                                           float* Ta, float* Tb, int t)
{
  int tr = t&15, tc = t>>4;
  stage68c(Pa, D_, Ta, t);
  stage68c(Pb, D_, Tb, t);
  __syncthreads();
  float acc[4][4] = {};
  for (int kk=0;kk<64;kk++){
    float4 av = *((const float4*)&Ta[kk*68 + tr*4]);
    float4 bv = *((const float4*)&Tb[kk*68 + tc*4]);
    float a[4]={av.x,av.y,av.z,av.w}, bb2[4]={bv.x,bv.y,bv.z,bv.w};
    #pragma unroll
    for (int u=0;u<4;u++)
      #pragma unroll
      for (int v=0;v<4;v++) acc[u][v] = fmaf(a[u], bb2[v], acc[u][v]);
  }
  #pragma unroll
  for (int u=0;u<4;u++){
    float4* pC = (float4*)(Cb + (size_t)(tr*4+u)*D_ + tc*4);
    float4 o = *pC;
    o.x -= acc[u][0]; o.y -= acc[u][1]; o.z -= acc[u][2]; o.w -= acc[u][3];
    *pC = o;
  }
  __syncthreads();
}

// panel: U <- invD * U
__device__ __forceinline__ void body_panel(float* __restrict__ U,
                                           const float* __restrict__ IDT,
                                           float* Ta, float* Tb, int t)
{
  int tr = t&15, tc = t>>4;
  stage68c(IDT, 64, Ta, t);
  stage68c(U, D_, Tb, t);
  __syncthreads();
  float acc[4][4] = {};
  for (int kk=0;kk<64;kk++){
    float4 av = *((const float4*)&Ta[kk*68 + tr*4]);
    float4 bv = *((const float4*)&Tb[kk*68 + tc*4]);
    float a[4]={av.x,av.y,av.z,av.w}, bb2[4]={bv.x,bv.y,bv.z,bv.w};
    #pragma unroll
    for (int u=0;u<4;u++)
      #pragma unroll
      for (int v=0;v<4;v++) acc[u][v] = fmaf(a[u], bb2[v], acc[u][v]);
  }
  __syncthreads();   // done reading Tb before anyone restages (same-block next task)
  #pragma unroll
  for (int u=0;u<4;u++){
    float4 o = make_float4(acc[u][0],acc[u][1],acc[u][2],acc[u][3]);
    *((float4*)(U + (size_t)(tr*4+u)*D_ + tc*4)) = o;
  }
  __syncthreads();
}

// fused: C(d,d) -= Pd^T Pd (optional), factor, 4-lane triangular inverse, write invDT
__device__ __forceinline__ void body_traildiag(const float* __restrict__ Pd,
                                               const float* __restrict__ Cd,
                                               float* __restrict__ Ig,
                                               float* Ta, float* Tb, int t, bool dosub)
{
  int tr = t&15, tc = t>>4;
  float acc[4][4] = {};
  if (dosub){
    stage68c(Pd, D_, Ta, t);
    __syncthreads();
    for (int kk=0;kk<64;kk++){
      float4 av = *((const float4*)&Ta[kk*68 + tr*4]);
      float4 bv = *((const float4*)&Ta[kk*68 + tc*4]);
      float a[4]={av.x,av.y,av.z,av.w}, bb2[4]={bv.x,bv.y,bv.z,bv.w};
      #pragma unroll
      for (int u=0;u<4;u++)
        #pragma unroll
        for (int v=0;v<4;v++) acc[u][v] = fmaf(a[u], bb2[v], acc[u][v]);
    }
    __syncthreads();
  }
  float* Ld = Ta;
  #pragma unroll
  for (int u=0;u<4;u++){
    float4 cv = *((const float4*)&Cd[(size_t)(tr*4+u)*D_ + tc*4]);
    cv.x -= acc[u][0]; cv.y -= acc[u][1]; cv.z -= acc[u][2]; cv.w -= acc[u][3];
    *((float4*)&Ld[(tr*4+u)*68 + tc*4]) = cv;
  }
  __syncthreads();
  for (int k=0;k<64;k++){
    if (t==0) Ld[k*68+k] = sqrtf(Ld[k*68+k]);
    __syncthreads();
    if (t>k && t<64) Ld[t*68+k] /= Ld[k*68+k];
    __syncthreads();
    for (int l=t; l<4096; l+=TPB){
      int r=l>>6, c=l&63;
      if (r>k && c>k) Ld[r*68+c] = fmaf(-Ld[r*68+k], Ld[c*68+k], Ld[r*68+c]);
    }
    __syncthreads();
  }
  // 4-lane-per-column register-resident triangular inverse; invDT[c][k2] = inv(k2,c)
  {
    int c = t>>2, s = t&3;
    float myv[16];
    #pragma unroll
    for (int i=0;i<16;i++) myv[i] = 0.f;
    if (s==0) myv[0] = 1.f/Ld[c*68+c];
    for (int r=c+1;r<64;r++){
      float partial = 0.f;
      #pragma unroll
      for (int idx=0; idx<16; idx++){
        int k2 = c + s + 4*idx;
        if (k2 < r) partial = fmaf(Ld[r*68+k2], myv[idx], partial);
      }
      partial += __shfl_xor(partial, 1, 64);
      partial += __shfl_xor(partial, 2, 64);
      float val = -partial / Ld[r*68+r];
      int d = r - c;
      #pragma unroll
      for (int idx=0; idx<16; idx++)
        if ((d & 3) == s && (d >> 2) == idx) myv[idx] = val;
    }
    #pragma unroll
    for (int idx=0; idx<16; idx++){
      int k2 = c + s + 4*idx;
      if (k2 < 64) Ig[c*64 + k2] = myv[idx];
    }
  }
  __syncthreads();
}

__global__ __launch_bounds__(256,4) void k_chol_coop(float* __restrict__ A,
                                                     float* __restrict__ invDT)
{
  cg::grid_group grid = cg::this_grid();
  __shared__ float sm[2*64*68];
  float* Ta = sm; float* Tb = sm + 64*68;
  int bid = blockIdx.x, t = threadIdx.x;
  int xcd = bid & 7, lb = bid >> 3;            // lb in [0,128)
  // diag(0)
  for (int lt=lb; lt<64; lt+=128){
    int m = mkm(xcd, lt);
    float* Am = A + (size_t)m*D_*D_;
    body_traildiag(nullptr, Am, invDT + ((size_t)m*8 + 0)*4096, Ta, Tb, t, false);
  }
  grid.sync();
  for (int j=0;j<7;j++){
    int nbp = 7-j;
    // panel phase
    for (int lt=lb; lt<64*nbp; lt+=128){
      int ti = lt>>6, ml = lt&63;
      int m = mkm(xcd, ml); int ib = j+1+ti;
      float* Am = A + (size_t)m*D_*D_;
      body_panel(Am + (size_t)(j*NB)*D_ + ib*NB,
                 invDT + ((size_t)m*8 + j)*4096, Ta, Tb, t);
    }
    grid.sync();
    // trail phase (z=0 task fused with diag(j+1))
    int np = nbp*(nbp+1)/2;
    for (int lt=lb; lt<64*np; lt+=128){
      int z = lt>>6, ml = lt&63;
      int m = mkm(xcd, ml);
      float* Am = A + (size_t)m*D_*D_;
      int p=0, zz=z; while (zz >= nbp-p){ zz -= nbp-p; p++; }
      int a = j+1+p, b = a+zz;
      if (z == 0){
        body_traildiag(Am + (size_t)(j*NB)*D_ + a*NB,
                       Am + (size_t)(a*NB)*D_ + a*NB,
                       invDT + ((size_t)m*8 + a)*4096, Ta, Tb, t, true);
      } else {
        body_trail(Am + (size_t)(j*NB)*D_ + a*NB,
                   Am + (size_t)(j*NB)*D_ + b*NB,
                   Am + (size_t)(a*NB)*D_ + b*NB, Ta, Tb, t);
      }
    }
    grid.sync();
  }
}

// ================= fallback (round-3 verbatim) =================
__global__ __launch_bounds__(TPB) void k_diag(float* __restrict__ A,
                                              float* __restrict__ invDT, int j)
{
  int m, t0; decode_mt(blockIdx.x, 1, m, t0); (void)t0;
  int t = threadIdx.x;
  __shared__ float Ld[64][65];
  __shared__ float Iv[64][65];
  float* Ab = A + (size_t)m*D_*D_ + (size_t)(j*NB)*D_ + j*NB;
  for (int l=t; l<4096; l+=TPB){ int r=l>>6, c=l&63; Ld[r][c] = Ab[(size_t)r*D_ + c]; Iv[r][c] = 0.f; }
  __syncthreads();
  for (int k=0;k<64;k++){
    if (t==0) Ld[k][k] = sqrtf(Ld[k][k]);
    __syncthreads();
    if (t>k && t<64) Ld[t][k] /= Ld[k][k];
    __syncthreads();
    for (int l=t; l<4096; l+=TPB){
      int r=l>>6, c=l&63;
      if (r>k && c>k) Ld[r][c] = fmaf(-Ld[r][k], Ld[c][k], Ld[r][c]);
    }
    __syncthreads();
  }
  if (t < 64){
    int c = t;
    Iv[c][c] = 1.f/Ld[c][c];
    for (int r=c+1;r<64;r++){
      float s = 0.f;
      for (int k2=c;k2<r;k2++) s += Ld[r][k2]*Iv[k2][c];
      Iv[r][c] = -s/Ld[r][r];
    }
  }
  __syncthreads();
  float* Ib = invDT + ((size_t)m*8 + j)*4096;
  for (int l=t; l<4096; l+=TPB){ Ib[l] = Iv[l&63][l>>6]; }
}

__global__ __launch_bounds__(TPB) void k_panel(float* __restrict__ A,
                                               const float* __restrict__ invDT,
                                               int j, int W)
{
  int m, ti; decode_mt(blockIdx.x, W, m, ti);
  int ib = j + 1 + ti;
  int t = threadIdx.x;
  __shared__ float Ta[64][68], Tb[64][68];
  float* U = A + (size_t)m*D_*D_ + (size_t)(j*NB)*D_ + ib*NB;
  body_panel(U, invDT + ((size_t)m*8 + j)*4096, &Ta[0][0], &Tb[0][0], t);
}

__global__ __launch_bounds__(TPB) void k_trail(float* __restrict__ A, int j, int W)
{
  int m, z; decode_mt(blockIdx.x, W, m, z);
  int T = NT - 1 - j;
  int p = 0; while (z >= T - p){ z -= T - p; p++; }
  int a2 = j + 1 + p, b2 = a2 + z;
  int t = threadIdx.x;
  __shared__ float Ta[64][68], Tb[64][68];
  float* Am = A + (size_t)m*D_*D_;
  body_trail(Am + (size_t)(j*NB)*D_ + a2*NB,
             Am + (size_t)(j*NB)*D_ + b2*NB,
             Am + (size_t)(a2*NB)*D_ + b2*NB, &Ta[0][0], &Tb[0][0], t);
}

// ---------------- fused rform + forward solve + maha + logits (round-3) ----------------
__global__ __launch_bounds__(TPB) void k_solvefin(const float* __restrict__ Qs,
                                                  const float* __restrict__ mu,
                                                  const float* __restrict__ A,
                                                  const float* __restrict__ invDT,
                                                  float* __restrict__ Z,
                                                  const int* __restrict__ qlen,
                                                  const float* __restrict__ lps,
                                                  float* __restrict__ out)
{
  int m, t0; decode_mt(blockIdx.x, 4, m, t0);
  int q0 = t0*NB;
  int b = m>>1, cls = m&1;
  int t = threadIdx.x, tr = t&15, tc = t>>4;
  __shared__ float Ta[64][68], Tb[64][68];
  const float* Am = A + (size_t)m*D_*D_;
  float* Zm = Z + (size_t)m*D_*Q_;
  const float* muv = mu + ((size_t)b*3 + cls)*D_;
  float cs[4] = {0.f,0.f,0.f,0.f};
  for (int j=0;j<NT;j++){
    stage_T(Qs + ((size_t)b*Q_ + q0)*D_ + j*NB, D_, Ta, t);
    __syncthreads();
    float acc[4][4];
    #pragma unroll
    for (int u=0;u<4;u++){
      float mrow = muv[j*NB + tr*4 + u];
      #pragma unroll
      for (int v=0;v<4;v++) acc[u][v] = mrow - Ta[tr*4+u][tc*4+v];
    }
    __syncthreads();
    for (int k=0;k<j;k++){
      stage_D(Am + (size_t)(k*NB)*D_ + j*NB, D_, Ta, t);
      { int r = t >> 2, seg = (t & 3)*16;
        const float4* s4 = (const float4*)(Zm + (size_t)(k*NB + r)*Q_ + q0 + seg);
        #pragma unroll
        for (int i=0;i<4;i++) *((float4*)&Tb[r][seg + i*4]) = s4[i];
      }
      __syncthreads();
      for (int kk=0;kk<64;kk++){
        float4 av = *((const float4*)&Ta[kk][tr*4]);
        float4 bv = *((const float4*)&Tb[kk][tc*4]);
        float a[4]={av.x,av.y,av.z,av.w}, bb2[4]={bv.x,bv.y,bv.z,bv.w};
        #pragma unroll
        for (int u=0;u<4;u++)
          #pragma unroll
          for (int v=0;v<4;v++) acc[u][v] = fmaf(-a[u], bb2[v], acc[u][v]);
      }
      __syncthreads();
    }
    #pragma unroll
    for (int u=0;u<4;u++)
      #pragma unroll
      for (int v=0;v<4;v++) Tb[tr*4+u][tc*4+v] = acc[u][v];
    stage_D(invDT + ((size_t)m*8 + j)*4096, 64, Ta, t);
    __syncthreads();
    float o4[4][4] = {};
    for (int kk=0;kk<64;kk++){
      float4 av = *((const float4*)&Ta[kk][tr*4]);
      float4 bv = *((const float4*)&Tb[kk][tc*4]);
      float a[4]={av.x,av.y,av.z,av.w}, bb2[4]={bv.x,bv.y,bv.z,bv.w};
      #pragma unroll
      for (int u=0;u<4;u++)
        #pragma unroll
        for (int v=0;v<4;v++) o4[u][v] = fmaf(a[u], bb2[v], o4[u][v]);
    }
    if (j < NT-1){
      #pragma unroll
      for (int u=0;u<4;u++){
        float4 o = make_float4(o4[u][0], o4[u][1], o4[u][2], o4[u][3]);
        *((float4*)(Zm + (size_t)(j*NB + tr*4+u)*Q_ + q0 + tc*4)) = o;
      }
    }
    #pragma unroll
    for (int u=0;u<4;u++)
      #pragma unroll
      for (int v=0;v<4;v++) cs[v] = fmaf(o4[u][v], o4[u][v], cs[v]);
    __syncthreads();
  }
  float* red = &Ta[0][0];
  #pragma unroll
  for (int v=0;v<4;v++) red[(tc*4+v)*16 + tr] = cs[v];
  __syncthreads();
  if (t < 64){
    float s = 0.f;
    #pragma unroll
    for (int i=0;i<16;i++) s += red[t*16 + i];
    int q = q0 + t;
    float valid = (q < qlen[b]) ? 1.f : 0.f;
    float s2 = expf(2.f*lps[0]);
    out[((size_t)b*Q_ + q)*2 + cls] = -s2*s*valid;
  }
}

extern "C" void kernel_launch(void* const* d_in, const int* in_sizes, int n_in,
                              void* d_out, int out_size, void* d_ws, size_t ws_size,
                              hipStream_t stream) {
  (void)in_sizes; (void)n_in; (void)out_size;
  const float* X   = (const float*)d_in[0];
  const int*   lab = (const int*)d_in[1];
  const float* Qs  = (const float*)d_in[2];
  const int*   sl  = (const int*)d_in[3];
  const int*   ql  = (const int*)d_in[4];
  const float* lps = (const float*)d_in[5];
  float* out = (float*)d_out;

  float* A  = (float*)d_ws;                          // [512,512,512] f32
  float* Z  = A + (size_t)NM_*D_*D_;                 // [512,512,256] f32 (overlaps Xvh/Xvl)
  unsigned short* Xvh = (unsigned short*)Z;          // [256,512,512] f16 bits
  unsigned short* Xvl = Xvh + (size_t)B_*D_*S_;      // [256,512,512] f16 bits
  float* invDT = Z + (size_t)NM_*D_*Q_;              // [512,8,64,64] f32 (transposed)
  float* mu   = invDT + (size_t)NM_*8*64*64;         // [256,3,512]
  float* cnt  = mu + (size_t)B_*3*D_;                // [256,2]
  unsigned int* wpbits = (unsigned int*)(cnt + B_*2);// [256,16]
  size_t need = (size_t)((char*)(wpbits + B_*16) - (char*)d_ws);
  if (ws_size < need) return;

  k_stats<<<dim3(B_), dim3(TPB), 0, stream>>>(X, lab, sl, mu, cnt, wpbits);
  k_prep<<<dim3(64, B_), dim3(TPB), 0, stream>>>(X, sl, Xvh, Xvl);
  k_gram<<<dim3(2560), dim3(TPB), 0, stream>>>(Xvh, Xvl, wpbits, mu, cnt, sl, A);

  // cooperative fused Cholesky; fallback to 24-launch chain if unsupported
  float* Aarg = A; float* Iarg = invDT;
  void* cargs[] = { (void*)&Aarg, (void*)&Iarg };
  hipError_t ce = hipLaunchCooperativeKernel((const void*)k_chol_coop,
                                             dim3(1024), dim3(256), cargs, 0, stream);
  if (ce != hipSuccess){
    (void)hipGetLastError();   // clear sticky error
    for (int j=0; j<NT; j++){
      k_diag<<<dim3(NM_), dim3(TPB), 0, stream>>>(A, invDT, j);
      int nb = NT-1-j;
      if (nb > 0) k_panel<<<dim3(NM_*nb), dim3(TPB), 0, stream>>>(A, invDT, j, nb);
      int np = nb*(nb+1)/2;
      if (np > 0) k_trail<<<dim3(NM_*np), dim3(TPB), 0, stream>>>(A, j, np);
    }
  }

  k_solvefin<<<dim3(NM_*4), dim3(TPB), 0, stream>>>(Qs, mu, A, invDT, Z, ql, lps, out);
}

// Round 6
// 3396.399 us; speedup vs baseline: 1.2805x; 1.2805x over previous
//
#include <hip/hip_runtime.h>
#include <hip/hip_bf16.h>

#define TPB 256
constexpr int B_ = 256, S_ = 512, D_ = 512, Q_ = 256, NM_ = 512;
constexpr int NB = 64, NT = 8;

typedef _Float16 f16x8 __attribute__((ext_vector_type(8)));
typedef float f32x4 __attribute__((ext_vector_type(4)));

// XCD-co-locating decode: x=bid&7 -> XCD; per XCD: tasks fastest, then cls, then group.
__device__ __forceinline__ void decode_mt(int bid, int W, int& m, int& t){
  int x = bid & 7, r = bid >> 3;
  t = r % W; int u = r / W;
  m = (((u >> 1)*8 + x) << 1) | (u & 1);
}

// direct row-major 64x64 stage into pitch-68 LDS (256 threads)
__device__ __forceinline__ void stage_D(const float* __restrict__ src, size_t ld,
                                        float (*dst)[68], int t)
{
  int r = t >> 2, seg = (t & 3) * 16;
  const float4* s4 = (const float4*)(src + (size_t)r*ld + seg);
  #pragma unroll
  for (int i=0;i<4;i++) *((float4*)&dst[r][seg + i*4]) = s4[i];
}
__device__ __forceinline__ void stage68c(const float* __restrict__ src, size_t ld,
                                         float* __restrict__ dst, int t)
{
  int r = t >> 2, seg = (t & 3) * 16;
  const float4* s4 = (const float4*)(src + (size_t)r*ld + seg);
  #pragma unroll
  for (int i=0;i<4;i++) *((float4*)&dst[r*68 + seg + i*4]) = s4[i];
}

// transposed stage: dst[col][row] = src[row][col]
__device__ __forceinline__ void stage_T(const float* __restrict__ src, size_t ld,
                                        float (*dst)[68], int t)
{
  int r = t >> 2, seg = (t & 3) * 16;
  const float4* s4 = (const float4*)(src + (size_t)r*ld + seg);
  #pragma unroll
  for (int i=0;i<4;i++){
    float4 v = s4[i];
    dst[seg + i*4 + 0][r] = v.x;
    dst[seg + i*4 + 1][r] = v.y;
    dst[seg + i*4 + 2][r] = v.z;
    dst[seg + i*4 + 3][r] = v.w;
  }
}

// acc[u][v] += sum_kk Aop[kk][tr*4+u] * Bop[kk][tc*4+v]   (pitch-68 operands)
__device__ __forceinline__ void mm_acc(const float* __restrict__ Aop,
                                       const float* __restrict__ Bop,
                                       float acc[4][4], int tr, int tc)
{
  for (int kk=0;kk<64;kk++){
    float4 av = *((const float4*)&Aop[kk*68 + tr*4]);
    float4 bv = *((const float4*)&Bop[kk*68 + tc*4]);
    float a[4]={av.x,av.y,av.z,av.w}, b2[4]={bv.x,bv.y,bv.z,bv.w};
    #pragma unroll
    for (int u=0;u<4;u++)
      #pragma unroll
      for (int v=0;v<4;v++) acc[u][v] = fmaf(a[u], b2[v], acc[u][v]);
  }
}

// ---------------- stats ----------------
__global__ __launch_bounds__(TPB) void k_stats(const float* __restrict__ X,
                                               const int* __restrict__ labels,
                                               const int* __restrict__ slen,
                                               float* __restrict__ mu,
                                               float* __restrict__ cnt,
                                               unsigned int* __restrict__ wpbits)
{
  int b = blockIdx.x, t = threadIdx.x;
  __shared__ int lab[S_];
  __shared__ float red[TPB];
  int L = slen[b];
  for (int s = t; s < S_; s += TPB) {
    int lb = labels[b*S_ + s];
    lab[s] = (s < L) ? lb : -1;
  }
  __syncthreads();
  if (t < 16) {
    unsigned int wword = 0;
    for (int i2 = 0; i2 < 32; i2++) if (lab[t*32 + i2] == 1) wword |= (1u << i2);
    wpbits[b*16 + t] = wword;
  }
  int cpi=0, cni=0;
  for (int s=t; s<S_; s+=TPB){ cpi += (lab[s]==1); cni += (lab[s]==0); }
  red[t] = (float)cpi; __syncthreads();
  for (int o=TPB/2;o>0;o>>=1){ if(t<o) red[t]+=red[t+o]; __syncthreads(); }
  float cp = red[0]; __syncthreads();
  red[t] = (float)cni; __syncthreads();
  for (int o=TPB/2;o>0;o>>=1){ if(t<o) red[t]+=red[t+o]; __syncthreads(); }
  float cn = red[0];
  if (t==0){ cnt[b*2+0]=cn; cnt[b*2+1]=cp; }
  float sp0=0,sp1=0,sn0=0,sn1=0;
  const float* Xb = X + (size_t)b*S_*D_;
  for (int s=0;s<S_;s++){
    int e = lab[s];
    if (e < 0) continue;
    float x0 = Xb[(size_t)s*D_ + t];
    float x1 = Xb[(size_t)s*D_ + t + 256];
    if (e==1){ sp0+=x0; sp1+=x1; } else { sn0+=x0; sn1+=x1; }
  }
  float stv = (float)L;
  float* mb = mu + (size_t)b*3*D_;
  mb[0*D_ + t] = sn0/cn;        mb[0*D_ + t+256] = sn1/cn;
  mb[1*D_ + t] = sp0/cp;        mb[1*D_ + t+256] = sp1/cp;
  mb[2*D_ + t] = (sn0+sp0)/stv; mb[2*D_ + t+256] = (sn1+sp1)/stv;
}

// ---------------- prep: transpose X -> f16 hi/lo [B][D][S], valid-masked ----------------
__global__ __launch_bounds__(TPB) void k_prep(const float* __restrict__ X,
                                              const int* __restrict__ slen,
                                              unsigned short* __restrict__ Xvh,
                                              unsigned short* __restrict__ Xvl)
{
  int b = blockIdx.y, z = blockIdx.x;
  int d0 = (z>>3)*64, s0 = (z&7)*64;
  int t = threadIdx.x;
  __shared__ float Tl[64][65];
  const float* src = X + ((size_t)b*S_ + s0)*D_ + d0;
  { int r = t>>2, seg = (t&3)*16;
    const float4* s4 = (const float4*)(src + (size_t)r*D_ + seg);
    #pragma unroll
    for (int i=0;i<4;i++){ float4 v = s4[i];
      Tl[seg+i*4+0][r]=v.x; Tl[seg+i*4+1][r]=v.y; Tl[seg+i*4+2][r]=v.z; Tl[seg+i*4+3][r]=v.w; } }
  __syncthreads();
  int L = slen[b];
  int dr = t>>2, sc = (t&3)*16;
  union U16 { unsigned short u[8]; uint4 v; };
  U16 H[2], Lo[2];
  #pragma unroll
  for (int g=0; g<2; g++)
    #pragma unroll
    for (int i=0;i<8;i++){
      int si = sc + g*8 + i;
      float x = (s0+si < L) ? Tl[dr][si] : 0.f;
      _Float16 hh = (_Float16)x;
      float lo = x - (float)hh;
      H[g].u[i]  = __builtin_bit_cast(unsigned short, hh);
      Lo[g].u[i] = __builtin_bit_cast(unsigned short, (_Float16)lo);
    }
  size_t o = ((size_t)b*D_ + d0+dr)*S_ + s0 + sc;
  *(uint4*)(Xvh+o)   = H[0].v;  *(uint4*)(Xvh+o+8) = H[1].v;
  *(uint4*)(Xvl+o)   = Lo[0].v; *(uint4*)(Xvl+o+8) = Lo[1].v;
}

// ---------------- MFMA Gram -> A matrices (upper 128-tiles incl. diagonal) ----------------
__global__ __launch_bounds__(TPB,2) void k_gram(const unsigned short* __restrict__ Xvh,
                                                const unsigned short* __restrict__ Xvl,
                                                const unsigned int* __restrict__ wpbits,
                                                const float* __restrict__ mu,
                                                const float* __restrict__ cnt,
                                                const int* __restrict__ slen,
                                                float* __restrict__ A)
{
  __shared__ unsigned short sAvh[128][32], sAvl[128][32], sAph[128][32], sApl[128][32],
                            sBvh[128][32], sBvl[128][32];
  int id = blockIdx.x;
  int g = id>>3;
  int b = (g/10)*8 + (id&7);
  int z = g%10;
  int ti=0; while (z >= 4-ti){ z -= 4-ti; ti++; } int tj = ti + z;
  int i0 = ti*128, j0 = tj*128;
  int t = threadIdx.x, lane = t&63, w = t>>6;
  int wr = w>>1, wc = w&1, l15 = lane&15;

  f32x4 acc_t[4][4], acc_p[4][4];
  f32x4 z4 = {0.f,0.f,0.f,0.f};
  #pragma unroll
  for (int mf=0;mf<4;mf++)
    #pragma unroll
    for (int nf=0;nf<4;nf++){ acc_t[mf][nf]=z4; acc_p[mf][nf]=z4; }

  const size_t baseA = ((size_t)b*D_ + i0)*S_;
  const size_t baseB = ((size_t)b*D_ + j0)*S_;
  int phx = (lane>>4) ^ ((l15>>1)&3);

  for (int ks=0; ks<16; ks++){
    int s0 = ks*32;
    unsigned int wpw = wpbits[b*16 + ks];
    __syncthreads();
    #pragma unroll
    for (int h=0; h<2; h++){
      int ci = t + h*256;
      int row = ci>>2, cpos = ci&3;
      int ph = cpos ^ ((row>>1)&3);
      size_t ga = baseA + (size_t)row*S_ + s0 + cpos*8;
      size_t gb = baseB + (size_t)row*S_ + s0 + cpos*8;
      uint4 vh = *(const uint4*)(Xvh+ga);
      uint4 vl = *(const uint4*)(Xvl+ga);
      uint4 bh = *(const uint4*)(Xvh+gb);
      uint4 bl = *(const uint4*)(Xvl+gb);
      unsigned int m8 = (wpw >> (cpos*8)) & 0xFFu;
      uint4 mk;
      mk.x = ((m8&1u)?0xFFFFu:0u)  | ((m8&2u)?0xFFFF0000u:0u);
      mk.y = ((m8&4u)?0xFFFFu:0u)  | ((m8&8u)?0xFFFF0000u:0u);
      mk.z = ((m8&16u)?0xFFFFu:0u) | ((m8&32u)?0xFFFF0000u:0u);
      mk.w = ((m8&64u)?0xFFFFu:0u) | ((m8&128u)?0xFFFF0000u:0u);
      uint4 p4, q4;
      p4.x = vh.x&mk.x; p4.y = vh.y&mk.y; p4.z = vh.z&mk.z; p4.w = vh.w&mk.w;
      q4.x = vl.x&mk.x; q4.y = vl.y&mk.y; q4.z = vl.z&mk.z; q4.w = vl.w&mk.w;
      *(uint4*)&sAvh[row][ph*8] = vh;
      *(uint4*)&sAvl[row][ph*8] = vl;
      *(uint4*)&sAph[row][ph*8] = p4;
      *(uint4*)&sApl[row][ph*8] = q4;
      *(uint4*)&sBvh[row][ph*8] = bh;
      *(uint4*)&sBvl[row][ph*8] = bl;
    }
    __syncthreads();
    f16x8 Avh[4], Avl[4], Aph[4], Apl[4];
    #pragma unroll
    for (int mf=0;mf<4;mf++){
      int r = wr*64 + mf*16 + l15;
      Avh[mf] = __builtin_bit_cast(f16x8, *(const uint4*)&sAvh[r][phx*8]);
      Avl[mf] = __builtin_bit_cast(f16x8, *(const uint4*)&sAvl[r][phx*8]);
      Aph[mf] = __builtin_bit_cast(f16x8, *(const uint4*)&sAph[r][phx*8]);
      Apl[mf] = __builtin_bit_cast(f16x8, *(const uint4*)&sApl[r][phx*8]);
    }
    #pragma unroll
    for (int nf=0;nf<4;nf++){
      int r = wc*64 + nf*16 + l15;
      f16x8 Bh = __builtin_bit_cast(f16x8, *(const uint4*)&sBvh[r][phx*8]);
      f16x8 Bl = __builtin_bit_cast(f16x8, *(const uint4*)&sBvl[r][phx*8]);
      #pragma unroll
      for (int mf=0;mf<4;mf++){
        acc_t[mf][nf] = __builtin_amdgcn_mfma_f32_16x16x32_f16(Avh[mf], Bh, acc_t[mf][nf],0,0,0);
        acc_t[mf][nf] = __builtin_amdgcn_mfma_f32_16x16x32_f16(Avh[mf], Bl, acc_t[mf][nf],0,0,0);
        acc_t[mf][nf] = __builtin_amdgcn_mfma_f32_16x16x32_f16(Avl[mf], Bh, acc_t[mf][nf],0,0,0);
        acc_p[mf][nf] = __builtin_amdgcn_mfma_f32_16x16x32_f16(Aph[mf], Bh, acc_p[mf][nf],0,0,0);
        acc_p[mf][nf] = __builtin_amdgcn_mfma_f32_16x16x32_f16(Aph[mf], Bl, acc_p[mf][nf],0,0,0);
        acc_p[mf][nf] = __builtin_amdgcn_mfma_f32_16x16x32_f16(Apl[mf], Bh, acc_p[mf][nf],0,0,0);
      }
    }
  }
  float cn = cnt[b*2+0], cp = cnt[b*2+1];
  float stv = (float)slen[b];
  float kn = 0.1f/(cn-1.f), kp = 0.1f/(cp-1.f), kt = 0.9f/(stv-1.f);
  float rn = 0.1f*cn/(cn-1.f), rp = 0.1f*cp/(cp-1.f), rt = 0.9f*stv/(stv-1.f);
  const float* mb = mu + (size_t)b*3*D_;
  float* A0 = A + (size_t)(b*2+0)*D_*D_;
  float* A1 = A + (size_t)(b*2+1)*D_*D_;
  int rbase = i0 + wr*64 + (lane>>4)*4;
  int cbase = j0 + wc*64 + l15;
  #pragma unroll
  for (int mf=0;mf<4;mf++){
    #pragma unroll
    for (int i=0;i<4;i++){
      int r = rbase + mf*16 + i;
      float mnr = mb[r], mpr = mb[D_+r], mtr = mb[2*D_+r];
      #pragma unroll
      for (int nf=0;nf<4;nf++){
        int c = cbase + nf*16;
        float mnc = mb[c], mpc = mb[D_+c], mtc = mb[2*D_+c];
        float gp = acc_p[mf][nf][i];
        float gt = acc_t[mf][nf][i];
        float gn = gt - gp;
        float diag = (r==c)?0.1f:0.f;
        A0[(size_t)r*D_ + c] = kn*gn + kt*gt - rn*mnr*mnc - rt*mtr*mtc + diag;
        A1[(size_t)r*D_ + c] = kp*gp + kt*gt - rp*mpr*mpc - rt*mtr*mtc + diag;
      }
    }
  }
}

// ---------------- diag body: factor C (in LDS Ld pitch 68), write invDT + W -> Cd ----------------
__device__ __forceinline__ void diag_finish(float* __restrict__ Cd,  // global: W out
                                            float* __restrict__ Ig,  // invDT out
                                            float* Ld, float* Tb, int t)
{
  // factor Ld (lower) in place
  for (int k=0;k<64;k++){
    if (t==0) Ld[k*68+k] = sqrtf(Ld[k*68+k]);
    __syncthreads();
    if (t>k && t<64) Ld[t*68+k] /= Ld[k*68+k];
    __syncthreads();
    for (int l=t; l<4096; l+=TPB){
      int r=l>>6, c=l&63;
      if (r>k && c>k) Ld[r*68+c] = fmaf(-Ld[r*68+k], Ld[c*68+k], Ld[r*68+c]);
    }
    __syncthreads();
  }
  // 4-lane-per-column register-resident triangular inverse (verified R5)
  int c = t>>2, s = t&3;
  float myv[16];
  #pragma unroll
  for (int i=0;i<16;i++) myv[i] = 0.f;
  if (s==0) myv[0] = 1.f/Ld[c*68+c];
  for (int r=c+1;r<64;r++){
    float partial = 0.f;
    #pragma unroll
    for (int idx=0; idx<16; idx++){
      int k2 = c + s + 4*idx;
      if (k2 < r) partial = fmaf(Ld[r*68+k2], myv[idx], partial);
    }
    partial += __shfl_xor(partial, 1, 64);
    partial += __shfl_xor(partial, 2, 64);
    float val = -partial / Ld[r*68+r];
    int d = r - c;
    #pragma unroll
    for (int idx=0; idx<16; idx++)
      if ((d & 3) == s && (d >> 2) == idx) myv[idx] = val;
  }
  #pragma unroll
  for (int idx=0; idx<16; idx++){
    int k2 = c + s + 4*idx;
    if (k2 < 64) Ig[c*64 + k2] = myv[idx];     // invDT[c][k2] = Iv[k2][c]
  }
  // build IvL[k][c] = Iv[k][c] in Tb for W = Iv^T Iv
  for (int l=t; l<4352; l+=TPB) Tb[l] = 0.f;
  __syncthreads();
  #pragma unroll
  for (int idx=0; idx<16; idx++){
    int k2 = c + s + 4*idx;
    if (k2 < 64) Tb[k2*68 + c] = myv[idx];
  }
  __syncthreads();
  int tr = t&15, tc = t>>4;
  float accW[4][4] = {};
  mm_acc(Tb, Tb, accW, tr, tc);                // W[r][c] = sum_k Iv[k][r] Iv[k][c]
  #pragma unroll
  for (int u=0;u<4;u++){
    float4 o = make_float4(accW[u][0],accW[u][1],accW[u][2],accW[u][3]);
    *((float4*)(Cd + (size_t)(tr*4+u)*D_ + tc*4)) = o;
  }
}

// ---------------- diag(0): factor upper(0,0), write invDT(0), W(0)->upper(0,0) ----------------
__global__ __launch_bounds__(TPB) void k_diag0(float* __restrict__ A, float* __restrict__ invDT)
{
  int m, du; decode_mt(blockIdx.x, 1, m, du); (void)du;
  int t = threadIdx.x;
  __shared__ float Ta[64*68], Tb[64*68];
  float* Am = A + (size_t)m*D_*D_;
  stage68c(Am, D_, Ta, t);
  __syncthreads();
  diag_finish(Am, invDT + (size_t)m*8*4096, Ta, Tb, t);
}

// ---------------- combined step j: panels + W-form trail (+fused diag j+1) ----------------
__global__ __launch_bounds__(TPB) void k_step(float* __restrict__ A,
                                              float* __restrict__ invDT,
                                              int j, int np, int tot)
{
  __shared__ float Ta[64*68], Tb[64*68];
  int m, z; decode_mt(blockIdx.x, tot, m, z);
  int t = threadIdx.x, tr = t&15, tc = t>>4;
  float* Am = A + (size_t)m*D_*D_;
  const float* Wj = Am + (size_t)(j*NB)*D_ + j*NB;      // W(j) stored in upper(j,j)

  if (z >= np){
    // ---- panel: rect(ti,j) = invD_j * U(j,ti) ----
    int ti = j + 1 + (z - np);
    stage68c(invDT + ((size_t)m*8 + j)*4096, 64, Ta, t); // Ta[kk][r] = inv[r][kk]
    stage68c(Am + (size_t)(j*NB)*D_ + ti*NB, D_, Tb, t); // Tb[kk][y] = U(j,ti)
    __syncthreads();
    float acc[4][4] = {};
    mm_acc(Ta, Tb, acc, tr, tc);                         // P[x][y]
    float* Lout = Am + (size_t)(ti*NB)*D_ + j*NB;        // lower rect
    #pragma unroll
    for (int u=0;u<4;u++){
      float4 o = make_float4(acc[u][0],acc[u][1],acc[u][2],acc[u][3]);
      *((float4*)(Lout + (size_t)(tr*4+u)*D_ + tc*4)) = o;
    }
    return;
  }

  // trail pair decode
  int Tn = NT - 1 - j;
  int p = 0, zz = z;
  while (zz >= Tn - p){ zz -= Tn - p; p++; }
  int a = j + 1 + p, b = a + zz;

  if (z == 0){
    // ---- fused: C(j+1,j+1) -= U^T W U, factor, invDT(j+1), W(j+1)->upper(j+1,j+1) ----
    const float* Ud = Am + (size_t)(j*NB)*D_ + (j+1)*NB;
    stage68c(Ud, D_, Ta, t);          // Ta[kk][y] = U
    stage68c(Wj, D_, Tb, t);          // Tb[kk][r] = W (symmetric)
    __syncthreads();
    float accT[4][4] = {};
    mm_acc(Tb, Ta, accT, tr, tc);     // T[r][q] = W*U
    __syncthreads();
    #pragma unroll
    for (int u=0;u<4;u++)
      #pragma unroll
      for (int v=0;v<4;v++) Tb[(tr*4+u)*68 + tc*4+v] = accT[u][v];   // Tb[kk][q] = T
    __syncthreads();
    float acc2[4][4] = {};
    mm_acc(Ta, Tb, acc2, tr, tc);     // U^T T
    __syncthreads();
    float* Cd = Am + (size_t)((j+1)*NB)*D_ + (j+1)*NB;
    #pragma unroll
    for (int u=0;u<4;u++){
      float4 cv = *((const float4*)(Cd + (size_t)(tr*4+u)*D_ + tc*4));
      cv.x -= acc2[u][0]; cv.y -= acc2[u][1]; cv.z -= acc2[u][2]; cv.w -= acc2[u][3];
      *((float4*)&Ta[(tr*4+u)*68 + tc*4]) = cv;
    }
    __syncthreads();
    diag_finish(Cd, invDT + ((size_t)m*8 + j+1)*4096, Ta, Tb, t);
    return;
  }

  // ---- trail: upper(a,b) -= U_a^T W U_b ----
  stage68c(Am + (size_t)(j*NB)*D_ + b*NB, D_, Ta, t);    // Ta[kk][q] = U_b
  stage68c(Wj, D_, Tb, t);                               // Tb[kk][r] = W
  __syncthreads();
  float accT[4][4] = {};
  mm_acc(Tb, Ta, accT, tr, tc);                          // T = W*U_b
  __syncthreads();
  #pragma unroll
  for (int u=0;u<4;u++)
    #pragma unroll
    for (int v=0;v<4;v++) Tb[(tr*4+u)*68 + tc*4+v] = accT[u][v];     // Tb[kk][q] = T
  stage68c(Am + (size_t)(j*NB)*D_ + a*NB, D_, Ta, t);    // Ta[kk][d] = U_a
  __syncthreads();
  float acc2[4][4] = {};
  mm_acc(Ta, Tb, acc2, tr, tc);                          // U_a^T T
  float* Cb = Am + (size_t)(a*NB)*D_ + b*NB;
  #pragma unroll
  for (int u=0;u<4;u++){
    float4* pC = (float4*)(Cb + (size_t)(tr*4+u)*D_ + tc*4);
    float4 o = *pC;
    o.x -= acc2[u][0]; o.y -= acc2[u][1]; o.z -= acc2[u][2]; o.w -= acc2[u][3];
    *pC = o;
  }
}

// ---------------- fused rform + forward solve + maha + logits ----------------
__global__ __launch_bounds__(TPB) void k_solvefin(const float* __restrict__ Qs,
                                                  const float* __restrict__ mu,
                                                  const float* __restrict__ A,
                                                  const float* __restrict__ invDT,
                                                  float* __restrict__ Z,
                                                  const int* __restrict__ qlen,
                                                  const float* __restrict__ lps,
                                                  float* __restrict__ out)
{
  int m, t0; decode_mt(blockIdx.x, 4, m, t0);
  int q0 = t0*NB;
  int b = m>>1, cls = m&1;
  int t = threadIdx.x, tr = t&15, tc = t>>4;
  __shared__ float Ta[64][68], Tb[64][68];
  const float* Am = A + (size_t)m*D_*D_;
  float* Zm = Z + (size_t)m*D_*Q_;
  const float* muv = mu + ((size_t)b*3 + cls)*D_;
  float cs[4] = {0.f,0.f,0.f,0.f};
  for (int j=0;j<NT;j++){
    stage_T(Qs + ((size_t)b*Q_ + q0)*D_ + j*NB, D_, Ta, t);
    __syncthreads();
    float acc[4][4];
    #pragma unroll
    for (int u=0;u<4;u++){
      float mrow = muv[j*NB + tr*4 + u];
      #pragma unroll
      for (int v=0;v<4;v++) acc[u][v] = mrow - Ta[tr*4+u][tc*4+v];
    }
    __syncthreads();
    for (int k=0;k<j;k++){
      // L(j,k) trsm'd panel stored at lower rect(j,k): [kk][d] orientation
      stage_D(Am + (size_t)(j*NB)*D_ + k*NB, D_, Ta, t);
      { int r = t >> 2, seg = (t & 3)*16;
        const float4* s4 = (const float4*)(Zm + (size_t)(k*NB + r)*Q_ + q0 + seg);
        #pragma unroll
        for (int i=0;i<4;i++) *((float4*)&Tb[r][seg + i*4]) = s4[i];
      }
      __syncthreads();
      for (int kk=0;kk<64;kk++){
        float4 av = *((const float4*)&Ta[kk][tr*4]);
        float4 bv = *((const float4*)&Tb[kk][tc*4]);
        float a[4]={av.x,av.y,av.z,av.w}, bb2[4]={bv.x,bv.y,bv.z,bv.w};
        #pragma unroll
        for (int u=0;u<4;u++)
          #pragma unroll
          for (int v=0;v<4;v++) acc[u][v] = fmaf(-a[u], bb2[v], acc[u][v]);
      }
      __syncthreads();
    }
    #pragma unroll
    for (int u=0;u<4;u++)
      #pragma unroll
      for (int v=0;v<4;v++) Tb[tr*4+u][tc*4+v] = acc[u][v];
    stage_D(invDT + ((size_t)m*8 + j)*4096, 64, Ta, t);
    __syncthreads();
    float o4[4][4] = {};
    for (int kk=0;kk<64;kk++){
      float4 av = *((const float4*)&Ta[kk][tr*4]);
      float4 bv = *((const float4*)&Tb[kk][tc*4]);
      float a[4]={av.x,av.y,av.z,av.w}, bb2[4]={bv.x,bv.y,bv.z,bv.w};
      #pragma unroll
      for (int u=0;u<4;u++)
        #pragma unroll
        for (int v=0;v<4;v++) o4[u][v] = fmaf(a[u], bb2[v], o4[u][v]);
    }
    if (j < NT-1){
      #pragma unroll
      for (int u=0;u<4;u++){
        float4 o = make_float4(o4[u][0], o4[u][1], o4[u][2], o4[u][3]);
        *((float4*)(Zm + (size_t)(j*NB + tr*4+u)*Q_ + q0 + tc*4)) = o;
      }
    }
    #pragma unroll
    for (int u=0;u<4;u++)
      #pragma unroll
      for (int v=0;v<4;v++) cs[v] = fmaf(o4[u][v], o4[u][v], cs[v]);
    __syncthreads();
  }
  float* red = &Ta[0][0];
  #pragma unroll
  for (int v=0;v<4;v++) red[(tc*4+v)*16 + tr] = cs[v];
  __syncthreads();
  if (t < 64){
    float s = 0.f;
    #pragma unroll
    for (int i=0;i<16;i++) s += red[t*16 + i];
    int q = q0 + t;
    float valid = (q < qlen[b]) ? 1.f : 0.f;
    float s2 = expf(2.f*lps[0]);
    out[((size_t)b*Q_ + q)*2 + cls] = -s2*s*valid;
  }
}

extern "C" void kernel_launch(void* const* d_in, const int* in_sizes, int n_in,
                              void* d_out, int out_size, void* d_ws, size_t ws_size,
                              hipStream_t stream) {
  (void)in_sizes; (void)n_in; (void)out_size;
  const float* X   = (const float*)d_in[0];
  const int*   lab = (const int*)d_in[1];
  const float* Qs  = (const float*)d_in[2];
  const int*   sl  = (const int*)d_in[3];
  const int*   ql  = (const int*)d_in[4];
  const float* lps = (const float*)d_in[5];
  float* out = (float*)d_out;

  float* A  = (float*)d_ws;                          // [512,512,512] f32
  float* Z  = A + (size_t)NM_*D_*D_;                 // [512,512,256] f32 (overlaps Xvh/Xvl)
  unsigned short* Xvh = (unsigned short*)Z;          // [256,512,512] f16 bits
  unsigned short* Xvl = Xvh + (size_t)B_*D_*S_;      // [256,512,512] f16 bits
  float* invDT = Z + (size_t)NM_*D_*Q_;              // [512,8,64,64] f32 (transposed)
  float* mu   = invDT + (size_t)NM_*8*64*64;         // [256,3,512]
  float* cnt  = mu + (size_t)B_*3*D_;                // [256,2]
  unsigned int* wpbits = (unsigned int*)(cnt + B_*2);// [256,16]
  size_t need = (size_t)((char*)(wpbits + B_*16) - (char*)d_ws);
  if (ws_size < need) return;

  k_stats<<<dim3(B_), dim3(TPB), 0, stream>>>(X, lab, sl, mu, cnt, wpbits);
  k_prep<<<dim3(64, B_), dim3(TPB), 0, stream>>>(X, sl, Xvh, Xvl);
  k_gram<<<dim3(2560), dim3(TPB), 0, stream>>>(Xvh, Xvl, wpbits, mu, cnt, sl, A);

  // 8-launch Cholesky: diag0, then 7 combined {panel + W-trail (+fused diag)} steps
  k_diag0<<<dim3(NM_), dim3(TPB), 0, stream>>>(A, invDT);
  for (int j=0; j<7; j++){
    int np = (7-j)*(8-j)/2;
    int nb = 7-j;
    int tot = np + nb;
    k_step<<<dim3(NM_*tot), dim3(TPB), 0, stream>>>(A, invDT, j, np, tot);
  }

  k_solvefin<<<dim3(NM_*4), dim3(TPB), 0, stream>>>(Qs, mu, A, invDT, Z, ql, lps, out);
}

// Round 7
// 2657.397 us; speedup vs baseline: 1.6366x; 1.2781x over previous
//
#include <hip/hip_runtime.h>
#include <hip/hip_bf16.h>

#define TPB 256
constexpr int B_ = 256, S_ = 512, D_ = 512, Q_ = 256, NM_ = 512;
constexpr int NB = 64, NT = 8;

typedef _Float16 f16x8 __attribute__((ext_vector_type(8)));
typedef float f32x4 __attribute__((ext_vector_type(4)));

// XCD-co-locating decode: x=bid&7 -> XCD; per XCD: tasks fastest, then cls, then group.
__device__ __forceinline__ void decode_mt(int bid, int W, int& m, int& t){
  int x = bid & 7, r = bid >> 3;
  t = r % W; int u = r / W;
  m = (((u >> 1)*8 + x) << 1) | (u & 1);
}

// direct row-major 64x64 stage into pitch-68 LDS (256 threads)
__device__ __forceinline__ void stage_D(const float* __restrict__ src, size_t ld,
                                        float (*dst)[68], int t)
{
  int r = t >> 2, seg = (t & 3) * 16;
  const float4* s4 = (const float4*)(src + (size_t)r*ld + seg);
  #pragma unroll
  for (int i=0;i<4;i++) *((float4*)&dst[r][seg + i*4]) = s4[i];
}

// acc[u][v] += sum_kk Aop[kk][tr*4+u] * Bop[kk][tc*4+v]
__device__ __forceinline__ void mm_acc68(const float (*Aop)[68], const float (*Bop)[68],
                                         float acc[4][4], int tr, int tc)
{
  for (int kk=0;kk<64;kk++){
    float4 av = *((const float4*)&Aop[kk][tr*4]);
    float4 bv = *((const float4*)&Bop[kk][tc*4]);
    float a[4]={av.x,av.y,av.z,av.w}, b2[4]={bv.x,bv.y,bv.z,bv.w};
    #pragma unroll
    for (int u=0;u<4;u++)
      #pragma unroll
      for (int v=0;v<4;v++) acc[u][v] = fmaf(a[u], b2[v], acc[u][v]);
  }
}

// ---------------- stats: counts, means, pos bitmask ----------------
__global__ __launch_bounds__(TPB) void k_stats(const float* __restrict__ X,
                                               const int* __restrict__ labels,
                                               const int* __restrict__ slen,
                                               float* __restrict__ mu,
                                               float* __restrict__ cnt,
                                               unsigned int* __restrict__ wpbits)
{
  int b = blockIdx.x, t = threadIdx.x;
  __shared__ int lab[S_];
  __shared__ float red[TPB];
  int L = slen[b];
  for (int s = t; s < S_; s += TPB) {
    int lb = labels[b*S_ + s];
    lab[s] = (s < L) ? lb : -1;
  }
  __syncthreads();
  if (t < 16) {
    unsigned int wword = 0;
    for (int i2 = 0; i2 < 32; i2++) if (lab[t*32 + i2] == 1) wword |= (1u << i2);
    wpbits[b*16 + t] = wword;
  }
  int cpi=0, cni=0;
  for (int s=t; s<S_; s+=TPB){ cpi += (lab[s]==1); cni += (lab[s]==0); }
  red[t] = (float)cpi; __syncthreads();
  for (int o=TPB/2;o>0;o>>=1){ if(t<o) red[t]+=red[t+o]; __syncthreads(); }
  float cp = red[0]; __syncthreads();
  red[t] = (float)cni; __syncthreads();
  for (int o=TPB/2;o>0;o>>=1){ if(t<o) red[t]+=red[t+o]; __syncthreads(); }
  float cn = red[0];
  if (t==0){ cnt[b*2+0]=cn; cnt[b*2+1]=cp; }
  float sp0=0,sp1=0,sn0=0,sn1=0;
  const float* Xb = X + (size_t)b*S_*D_;
  for (int s=0;s<S_;s++){
    int e = lab[s];
    if (e < 0) continue;
    float x0 = Xb[(size_t)s*D_ + t];
    float x1 = Xb[(size_t)s*D_ + t + 256];
    if (e==1){ sp0+=x0; sp1+=x1; } else { sn0+=x0; sn1+=x1; }
  }
  float stv = (float)L;
  float* mb = mu + (size_t)b*3*D_;
  mb[0*D_ + t] = sn0/cn;        mb[0*D_ + t+256] = sn1/cn;
  mb[1*D_ + t] = sp0/cp;        mb[1*D_ + t+256] = sp1/cp;
  mb[2*D_ + t] = (sn0+sp0)/stv; mb[2*D_ + t+256] = (sn1+sp1)/stv;
}

// ---------------- prep: transpose X -> f16 hi/lo [B][D][S], valid-masked ----------------
__global__ __launch_bounds__(TPB) void k_prep(const float* __restrict__ X,
                                              const int* __restrict__ slen,
                                              unsigned short* __restrict__ Xvh,
                                              unsigned short* __restrict__ Xvl)
{
  int b = blockIdx.y, z = blockIdx.x;
  int d0 = (z>>3)*64, s0 = (z&7)*64;
  int t = threadIdx.x;
  __shared__ float Tl[64][65];
  const float* src = X + ((size_t)b*S_ + s0)*D_ + d0;
  { int r = t>>2, seg = (t&3)*16;
    const float4* s4 = (const float4*)(src + (size_t)r*D_ + seg);
    #pragma unroll
    for (int i=0;i<4;i++){ float4 v = s4[i];
      Tl[seg+i*4+0][r]=v.x; Tl[seg+i*4+1][r]=v.y; Tl[seg+i*4+2][r]=v.z; Tl[seg+i*4+3][r]=v.w; } }
  __syncthreads();
  int L = slen[b];
  int dr = t>>2, sc = (t&3)*16;
  union U16 { unsigned short u[8]; uint4 v; };
  U16 H[2], Lo[2];
  #pragma unroll
  for (int g=0; g<2; g++)
    #pragma unroll
    for (int i=0;i<8;i++){
      int si = sc + g*8 + i;
      float x = (s0+si < L) ? Tl[dr][si] : 0.f;
      _Float16 hh = (_Float16)x;
      float lo = x - (float)hh;
      H[g].u[i]  = __builtin_bit_cast(unsigned short, hh);
      Lo[g].u[i] = __builtin_bit_cast(unsigned short, (_Float16)lo);
    }
  size_t o = ((size_t)b*D_ + d0+dr)*S_ + s0 + sc;
  *(uint4*)(Xvh+o)   = H[0].v;  *(uint4*)(Xvh+o+8) = H[1].v;
  *(uint4*)(Xvl+o)   = Lo[0].v; *(uint4*)(Xvl+o+8) = Lo[1].v;
}

// ---------------- MFMA Gram -> A matrices (upper 128-tiles incl. diagonal) ----------------
__global__ __launch_bounds__(TPB,2) void k_gram(const unsigned short* __restrict__ Xvh,
                                                const unsigned short* __restrict__ Xvl,
                                                const unsigned int* __restrict__ wpbits,
                                                const float* __restrict__ mu,
                                                const float* __restrict__ cnt,
                                                const int* __restrict__ slen,
                                                float* __restrict__ A)
{
  __shared__ unsigned short sAvh[128][32], sAvl[128][32], sAph[128][32], sApl[128][32],
                            sBvh[128][32], sBvl[128][32];
  int id = blockIdx.x;
  int g = id>>3;
  int b = (g/10)*8 + (id&7);
  int z = g%10;
  int ti=0; while (z >= 4-ti){ z -= 4-ti; ti++; } int tj = ti + z;
  int i0 = ti*128, j0 = tj*128;
  int t = threadIdx.x, lane = t&63, w = t>>6;
  int wr = w>>1, wc = w&1, l15 = lane&15;

  f32x4 acc_t[4][4], acc_p[4][4];
  f32x4 z4 = {0.f,0.f,0.f,0.f};
  #pragma unroll
  for (int mf=0;mf<4;mf++)
    #pragma unroll
    for (int nf=0;nf<4;nf++){ acc_t[mf][nf]=z4; acc_p[mf][nf]=z4; }

  const size_t baseA = ((size_t)b*D_ + i0)*S_;
  const size_t baseB = ((size_t)b*D_ + j0)*S_;
  int phx = (lane>>4) ^ ((l15>>1)&3);

  for (int ks=0; ks<16; ks++){
    int s0 = ks*32;
    unsigned int wpw = wpbits[b*16 + ks];
    __syncthreads();
    #pragma unroll
    for (int h=0; h<2; h++){
      int ci = t + h*256;
      int row = ci>>2, cpos = ci&3;
      int ph = cpos ^ ((row>>1)&3);
      size_t ga = baseA + (size_t)row*S_ + s0 + cpos*8;
      size_t gb = baseB + (size_t)row*S_ + s0 + cpos*8;
      uint4 vh = *(const uint4*)(Xvh+ga);
      uint4 vl = *(const uint4*)(Xvl+ga);
      uint4 bh = *(const uint4*)(Xvh+gb);
      uint4 bl = *(const uint4*)(Xvl+gb);
      unsigned int m8 = (wpw >> (cpos*8)) & 0xFFu;
      uint4 mk;
      mk.x = ((m8&1u)?0xFFFFu:0u)  | ((m8&2u)?0xFFFF0000u:0u);
      mk.y = ((m8&4u)?0xFFFFu:0u)  | ((m8&8u)?0xFFFF0000u:0u);
      mk.z = ((m8&16u)?0xFFFFu:0u) | ((m8&32u)?0xFFFF0000u:0u);
      mk.w = ((m8&64u)?0xFFFFu:0u) | ((m8&128u)?0xFFFF0000u:0u);
      uint4 p4, q4;
      p4.x = vh.x&mk.x; p4.y = vh.y&mk.y; p4.z = vh.z&mk.z; p4.w = vh.w&mk.w;
      q4.x = vl.x&mk.x; q4.y = vl.y&mk.y; q4.z = vl.z&mk.z; q4.w = vl.w&mk.w;
      *(uint4*)&sAvh[row][ph*8] = vh;
      *(uint4*)&sAvl[row][ph*8] = vl;
      *(uint4*)&sAph[row][ph*8] = p4;
      *(uint4*)&sApl[row][ph*8] = q4;
      *(uint4*)&sBvh[row][ph*8] = bh;
      *(uint4*)&sBvl[row][ph*8] = bl;
    }
    __syncthreads();
    f16x8 Avh[4], Avl[4], Aph[4], Apl[4];
    #pragma unroll
    for (int mf=0;mf<4;mf++){
      int r = wr*64 + mf*16 + l15;
      Avh[mf] = __builtin_bit_cast(f16x8, *(const uint4*)&sAvh[r][phx*8]);
      Avl[mf] = __builtin_bit_cast(f16x8, *(const uint4*)&sAvl[r][phx*8]);
      Aph[mf] = __builtin_bit_cast(f16x8, *(const uint4*)&sAph[r][phx*8]);
      Apl[mf] = __builtin_bit_cast(f16x8, *(const uint4*)&sApl[r][phx*8]);
    }
    #pragma unroll
    for (int nf=0;nf<4;nf++){
      int r = wc*64 + nf*16 + l15;
      f16x8 Bh = __builtin_bit_cast(f16x8, *(const uint4*)&sBvh[r][phx*8]);
      f16x8 Bl = __builtin_bit_cast(f16x8, *(const uint4*)&sBvl[r][phx*8]);
      #pragma unroll
      for (int mf=0;mf<4;mf++){
        acc_t[mf][nf] = __builtin_amdgcn_mfma_f32_16x16x32_f16(Avh[mf], Bh, acc_t[mf][nf],0,0,0);
        acc_t[mf][nf] = __builtin_amdgcn_mfma_f32_16x16x32_f16(Avh[mf], Bl, acc_t[mf][nf],0,0,0);
        acc_t[mf][nf] = __builtin_amdgcn_mfma_f32_16x16x32_f16(Avl[mf], Bh, acc_t[mf][nf],0,0,0);
        acc_p[mf][nf] = __builtin_amdgcn_mfma_f32_16x16x32_f16(Aph[mf], Bh, acc_p[mf][nf],0,0,0);
        acc_p[mf][nf] = __builtin_amdgcn_mfma_f32_16x16x32_f16(Aph[mf], Bl, acc_p[mf][nf],0,0,0);
        acc_p[mf][nf] = __builtin_amdgcn_mfma_f32_16x16x32_f16(Apl[mf], Bh, acc_p[mf][nf],0,0,0);
      }
    }
  }
  float cn = cnt[b*2+0], cp = cnt[b*2+1];
  float stv = (float)slen[b];
  float kn = 0.1f/(cn-1.f), kp = 0.1f/(cp-1.f), kt = 0.9f/(stv-1.f);
  float rn = 0.1f*cn/(cn-1.f), rp = 0.1f*cp/(cp-1.f), rt = 0.9f*stv/(stv-1.f);
  const float* mb = mu + (size_t)b*3*D_;
  float* A0 = A + (size_t)(b*2+0)*D_*D_;
  float* A1 = A + (size_t)(b*2+1)*D_*D_;
  int rbase = i0 + wr*64 + (lane>>4)*4;
  int cbase = j0 + wc*64 + l15;
  #pragma unroll
  for (int mf=0;mf<4;mf++){
    #pragma unroll
    for (int i=0;i<4;i++){
      int r = rbase + mf*16 + i;
      float mnr = mb[r], mpr = mb[D_+r], mtr = mb[2*D_+r];
      #pragma unroll
      for (int nf=0;nf<4;nf++){
        int c = cbase + nf*16;
        float mnc = mb[c], mpc = mb[D_+c], mtc = mb[2*D_+c];
        float gp = acc_p[mf][nf][i];
        float gt = acc_t[mf][nf][i];
        float gn = gt - gp;
        float diag = (r==c)?0.1f:0.f;
        A0[(size_t)r*D_ + c] = kn*gn + kt*gt - rn*mnr*mnc - rt*mtr*mtc + diag;
        A1[(size_t)r*D_ + c] = kp*gp + kt*gt - rp*mpr*mpc - rt*mtr*mtc + diag;
      }
    }
  }
}

// ---------------- diag block Cholesky + triangular inverse (transposed out) ----------------
__global__ __launch_bounds__(TPB) void k_diag(float* __restrict__ A,
                                              float* __restrict__ invDT, int j)
{
  int m, t0; decode_mt(blockIdx.x, 1, m, t0); (void)t0;
  int t = threadIdx.x;
  __shared__ float Ld[64][65];
  __shared__ float Iv[64][65];
  float* Ab = A + (size_t)m*D_*D_ + (size_t)(j*NB)*D_ + j*NB;   // upper(j,j)
  for (int l=t; l<4096; l+=TPB){ int r=l>>6, c=l&63; Ld[r][c] = Ab[(size_t)r*D_ + c]; Iv[r][c] = 0.f; }
  __syncthreads();
  for (int k=0;k<64;k++){
    if (t==0) Ld[k][k] = sqrtf(Ld[k][k]);
    __syncthreads();
    if (t>k && t<64) Ld[t][k] /= Ld[k][k];
    __syncthreads();
    for (int l=t; l<4096; l+=TPB){
      int r=l>>6, c=l&63;
      if (r>k && c>k) Ld[r][c] = fmaf(-Ld[r][k], Ld[c][k], Ld[r][c]);
    }
    __syncthreads();
  }
  if (t < 64){
    int c = t;
    Iv[c][c] = 1.f/Ld[c][c];
    for (int r=c+1;r<64;r++){
      float s = 0.f;
      for (int k2=c;k2<r;k2++) s += Ld[r][k2]*Iv[k2][c];
      Iv[r][c] = -s/Ld[r][r];
    }
  }
  __syncthreads();
  float* Ib = invDT + ((size_t)m*8 + j)*4096;
  for (int l=t; l<4096; l+=TPB){ Ib[l] = Iv[l&63][l>>6]; }   // invDT[k][r] = invD[r][k]
}

// ---------------- panel: upper(j,ib) <- invD * upper(j,ib)   (= L_ib,j^T) ----------------
__global__ __launch_bounds__(TPB) void k_panel(float* __restrict__ A,
                                               const float* __restrict__ invDT,
                                               int j, int W)
{
  int m, ti; decode_mt(blockIdx.x, W, m, ti);
  int ib = j + 1 + ti;
  int t = threadIdx.x, tr = t&15, tc = t>>4;
  __shared__ float Ta[64][68], Tb[64][68];
  float* U = A + (size_t)m*D_*D_ + (size_t)(j*NB)*D_ + ib*NB;
  stage_D(invDT + ((size_t)m*8 + j)*4096, 64, Ta, t);   // Ta[kk][r] = invD[r][kk]
  stage_D(U, D_, Tb, t);                                 // Tb[kk][c] = U[kk][c]
  __syncthreads();
  float acc[4][4] = {};
  mm_acc68(Ta, Tb, acc, tr, tc);
  #pragma unroll
  for (int u=0;u<4;u++){
    float4 o = make_float4(acc[u][0],acc[u][1],acc[u][2],acc[u][3]);
    *((float4*)(U + (size_t)(tr*4+u)*D_ + tc*4)) = o;
  }
}

// ---------------- trailrow: upper(row,b) -= U(j,row)^T U(j,b), b=row..7 ----------------
__global__ __launch_bounds__(TPB) void k_trailrow(float* __restrict__ A, int j, int row, int W)
{
  int m, z; decode_mt(blockIdx.x, W, m, z);
  int b2 = row + z;
  int t = threadIdx.x, tr = t&15, tc = t>>4;
  __shared__ float Ta[64][68], Tb[64][68];
  float* Am = A + (size_t)m*D_*D_;
  stage_D(Am + (size_t)(j*NB)*D_ + row*NB, D_, Ta, t);
  stage_D(Am + (size_t)(j*NB)*D_ + b2*NB, D_, Tb, t);
  __syncthreads();
  float acc[4][4] = {};
  mm_acc68(Ta, Tb, acc, tr, tc);
  float* Cb = Am + (size_t)(row*NB)*D_ + b2*NB;
  #pragma unroll
  for (int u=0;u<4;u++){
    float4* pC = (float4*)(Cb + (size_t)(tr*4+u)*D_ + tc*4);
    float4 o = *pC;
    o.x -= acc[u][0]; o.y -= acc[u][1]; o.z -= acc[u][2]; o.w -= acc[u][3];
    *pC = o;
  }
}

// ---------------- trail2: upper(a,b) -= U(jb,a)^T U(jb,b) + U(jb+1,a)^T U(jb+1,b) ----------------
// pairs a<=b in [jb+2, 7]; one RMW per tile for two K-64 updates
__global__ __launch_bounds__(TPB) void k_trail2(float* __restrict__ A, int jb, int W)
{
  int m, z; decode_mt(blockIdx.x, W, m, z);
  int base = jb + 2;
  int Tn = NT - base;
  int p = 0, zz = z;
  while (zz >= Tn - p){ zz -= Tn - p; p++; }
  int a2 = base + p, b2 = a2 + zz;
  int t = threadIdx.x, tr = t&15, tc = t>>4;
  __shared__ float Ta[64][68], Tb[64][68];
  float* Am = A + (size_t)m*D_*D_;
  float acc[4][4] = {};
  stage_D(Am + (size_t)(jb*NB)*D_ + a2*NB, D_, Ta, t);
  stage_D(Am + (size_t)(jb*NB)*D_ + b2*NB, D_, Tb, t);
  __syncthreads();
  mm_acc68(Ta, Tb, acc, tr, tc);
  __syncthreads();
  stage_D(Am + (size_t)((jb+1)*NB)*D_ + a2*NB, D_, Ta, t);
  stage_D(Am + (size_t)((jb+1)*NB)*D_ + b2*NB, D_, Tb, t);
  __syncthreads();
  mm_acc68(Ta, Tb, acc, tr, tc);
  float* Cb = Am + (size_t)(a2*NB)*D_ + b2*NB;
  #pragma unroll
  for (int u=0;u<4;u++){
    float4* pC = (float4*)(Cb + (size_t)(tr*4+u)*D_ + tc*4);
    float4 o = *pC;
    o.x -= acc[u][0]; o.y -= acc[u][1]; o.z -= acc[u][2]; o.w -= acc[u][3];
    *pC = o;
  }
}

// ---------------- fused rform + forward solve + maha + logits ----------------
__global__ __launch_bounds__(TPB) void k_solvefin(const float* __restrict__ Qs,
                                                  const float* __restrict__ mu,
                                                  const float* __restrict__ A,
                                                  const float* __restrict__ invDT,
                                                  float* __restrict__ Z,
                                                  const int* __restrict__ qlen,
                                                  const float* __restrict__ lps,
                                                  float* __restrict__ out)
{
  int m, t0; decode_mt(blockIdx.x, 4, m, t0);
  int q0 = t0*NB;
  int b = m>>1, cls = m&1;
  int t = threadIdx.x, tr = t&15, tc = t>>4;
  __shared__ float Ta[64][68], Tb[64][68];
  const float* Am = A + (size_t)m*D_*D_;
  float* Zm = Z + (size_t)m*D_*Q_;
  const float* muv = mu + ((size_t)b*3 + cls)*D_;
  float cs[4] = {0.f,0.f,0.f,0.f};
  for (int j=0;j<NT;j++){
    // init acc = mu - Qs^T via direct coalesced reads (no LDS transpose)
    float acc[4][4];
    {
      float4 mv = *(const float4*)&muv[j*NB + tr*4];
      #pragma unroll
      for (int v=0;v<4;v++){
        float4 qv = *(const float4*)&Qs[((size_t)b*Q_ + q0 + tc*4 + v)*D_ + j*NB + tr*4];
        acc[0][v] = mv.x - qv.x;
        acc[1][v] = mv.y - qv.y;
        acc[2][v] = mv.z - qv.z;
        acc[3][v] = mv.w - qv.w;
      }
    }
    for (int k=0;k<j;k++){
      stage_D(Am + (size_t)(k*NB)*D_ + j*NB, D_, Ta, t);   // Ta[kk][r] = L_jk[r][kk]
      { int r = t >> 2, seg = (t & 3)*16;
        const float4* s4 = (const float4*)(Zm + (size_t)(k*NB + r)*Q_ + q0 + seg);
        #pragma unroll
        for (int i=0;i<4;i++) *((float4*)&Tb[r][seg + i*4]) = s4[i];
      }
      __syncthreads();
      for (int kk=0;kk<64;kk++){
        float4 av = *((const float4*)&Ta[kk][tr*4]);
        float4 bv = *((const float4*)&Tb[kk][tc*4]);
        float a[4]={av.x,av.y,av.z,av.w}, bb2[4]={bv.x,bv.y,bv.z,bv.w};
        #pragma unroll
        for (int u=0;u<4;u++)
          #pragma unroll
          for (int v=0;v<4;v++) acc[u][v] = fmaf(-a[u], bb2[v], acc[u][v]);
      }
      __syncthreads();
    }
    // Z_j = invD * S
    #pragma unroll
    for (int u=0;u<4;u++)
      #pragma unroll
      for (int v=0;v<4;v++) Tb[tr*4+u][tc*4+v] = acc[u][v];
    stage_D(invDT + ((size_t)m*8 + j)*4096, 64, Ta, t);    // Ta[kk][r] = invD[r][kk]
    __syncthreads();
    float o4[4][4] = {};
    for (int kk=0;kk<64;kk++){
      float4 av = *((const float4*)&Ta[kk][tr*4]);
      float4 bv = *((const float4*)&Tb[kk][tc*4]);
      float a[4]={av.x,av.y,av.z,av.w}, bb2[4]={bv.x,bv.y,bv.z,bv.w};
      #pragma unroll
      for (int u=0;u<4;u++)
        #pragma unroll
        for (int v=0;v<4;v++) o4[u][v] = fmaf(a[u], bb2[v], o4[u][v]);
    }
    if (j < NT-1){
      #pragma unroll
      for (int u=0;u<4;u++){
        float4 o = make_float4(o4[u][0], o4[u][1], o4[u][2], o4[u][3]);
        *((float4*)(Zm + (size_t)(j*NB + tr*4+u)*Q_ + q0 + tc*4)) = o;
      }
    }
    #pragma unroll
    for (int u=0;u<4;u++)
      #pragma unroll
      for (int v=0;v<4;v++) cs[v] = fmaf(o4[u][v], o4[u][v], cs[v]);
    __syncthreads();
  }
  float* red = &Ta[0][0];
  #pragma unroll
  for (int v=0;v<4;v++) red[(tc*4+v)*16 + tr] = cs[v];
  __syncthreads();
  if (t < 64){
    float s = 0.f;
    #pragma unroll
    for (int i=0;i<16;i++) s += red[t*16 + i];
    int q = q0 + t;
    float valid = (q < qlen[b]) ? 1.f : 0.f;
    float s2 = expf(2.f*lps[0]);
    out[((size_t)b*Q_ + q)*2 + cls] = -s2*s*valid;
  }
}

extern "C" void kernel_launch(void* const* d_in, const int* in_sizes, int n_in,
                              void* d_out, int out_size, void* d_ws, size_t ws_size,
                              hipStream_t stream) {
  (void)in_sizes; (void)n_in; (void)out_size;
  const float* X   = (const float*)d_in[0];
  const int*   lab = (const int*)d_in[1];
  const float* Qs  = (const float*)d_in[2];
  const int*   sl  = (const int*)d_in[3];
  const int*   ql  = (const int*)d_in[4];
  const float* lps = (const float*)d_in[5];
  float* out = (float*)d_out;

  float* A  = (float*)d_ws;                          // [512,512,512] f32
  float* Z  = A + (size_t)NM_*D_*D_;                 // [512,512,256] f32 (overlaps Xvh/Xvl)
  unsigned short* Xvh = (unsigned short*)Z;          // [256,512,512] f16 bits
  unsigned short* Xvl = Xvh + (size_t)B_*D_*S_;      // [256,512,512] f16 bits
  float* invDT = Z + (size_t)NM_*D_*Q_;              // [512,8,64,64] f32 (transposed)
  float* mu   = invDT + (size_t)NM_*8*64*64;         // [256,3,512]
  float* cnt  = mu + (size_t)B_*3*D_;                // [256,2]
  unsigned int* wpbits = (unsigned int*)(cnt + B_*2);// [256,16]
  size_t need = (size_t)((char*)(wpbits + B_*16) - (char*)d_ws);
  if (ws_size < need) return;

  k_stats<<<dim3(B_), dim3(TPB), 0, stream>>>(X, lab, sl, mu, cnt, wpbits);
  k_prep<<<dim3(64, B_), dim3(TPB), 0, stream>>>(X, sl, Xvh, Xvl);
  k_gram<<<dim3(2560), dim3(TPB), 0, stream>>>(Xvh, Xvl, wpbits, mu, cnt, sl, A);

  // lazy two-column Cholesky: per pair (j, j+1):
  //   diag(j); panel(j); trailrow(j -> col j+1); diag(j+1); panel(j+1); trail2(j..j+1 -> rest)
  for (int j=0; j<NT; j+=2){
    k_diag<<<dim3(NM_), dim3(TPB), 0, stream>>>(A, invDT, j);
    int nb0 = NT-1-j;
    if (nb0 > 0){
      k_panel<<<dim3(NM_*nb0), dim3(TPB), 0, stream>>>(A, invDT, j, nb0);
      int wr = NT - (j+1);            // tiles in row j+1: b = j+1 .. 7
      k_trailrow<<<dim3(NM_*wr), dim3(TPB), 0, stream>>>(A, j, j+1, wr);
      k_diag<<<dim3(NM_), dim3(TPB), 0, stream>>>(A, invDT, j+1);
      int nb1 = NT-1-(j+1);
      if (nb1 > 0){
        k_panel<<<dim3(NM_*nb1), dim3(TPB), 0, stream>>>(A, invDT, j+1, nb1);
        int Tn = NT - (j+2);
        int np = Tn*(Tn+1)/2;
        if (np > 0) k_trail2<<<dim3(NM_*np), dim3(TPB), 0, stream>>>(A, j, np);
      }
    }
  }

  k_solvefin<<<dim3(NM_*4), dim3(TPB), 0, stream>>>(Qs, mu, A, invDT, Z, ql, lps, out);
}

// Round 8
// 2444.733 us; speedup vs baseline: 1.7790x; 1.0870x over previous
//
#include <hip/hip_runtime.h>
#include <hip/hip_bf16.h>

#define TPB 256
constexpr int B_ = 256, S_ = 512, D_ = 512, Q_ = 256, NM_ = 512;
constexpr int NB = 64, NT = 8;

typedef _Float16 f16x8 __attribute__((ext_vector_type(8)));
typedef float f32x4 __attribute__((ext_vector_type(4)));

__device__ __forceinline__ int pidx(int j, int a){ return j*(15-j)/2 + (a-j-1); } // j<a, 28 tiles

// XCD-co-locating decode: x=bid&7 -> XCD; per XCD: tasks fastest, then cls, then group.
__device__ __forceinline__ void decode_mt(int bid, int W, int& m, int& t){
  int x = bid & 7, r = bid >> 3;
  t = r % W; int u = r / W;
  m = (((u >> 1)*8 + x) << 1) | (u & 1);
}

// direct row-major 64x64 stage into pitch-68 LDS (256 threads)
__device__ __forceinline__ void stage_D(const float* __restrict__ src, size_t ld,
                                        float (*dst)[68], int t)
{
  int r = t >> 2, seg = (t & 3) * 16;
  const float4* s4 = (const float4*)(src + (size_t)r*ld + seg);
  #pragma unroll
  for (int i=0;i<4;i++) *((float4*)&dst[r][seg + i*4]) = s4[i];
}

// acc[u][v] += sum_kk Aop[kk][tr*4+u] * Bop[kk][tc*4+v]
__device__ __forceinline__ void mm_acc68(const float (*Aop)[68], const float (*Bop)[68],
                                         float acc[4][4], int tr, int tc)
{
  for (int kk=0;kk<64;kk++){
    float4 av = *((const float4*)&Aop[kk][tr*4]);
    float4 bv = *((const float4*)&Bop[kk][tc*4]);
    float a[4]={av.x,av.y,av.z,av.w}, b2[4]={bv.x,bv.y,bv.z,bv.w};
    #pragma unroll
    for (int u=0;u<4;u++)
      #pragma unroll
      for (int v=0;v<4;v++) acc[u][v] = fmaf(a[u], b2[v], acc[u][v]);
  }
}

// ---------------- stats: counts, means, pos bitmask (1024 thr, 4-way s-split) ----------------
__global__ __launch_bounds__(1024) void k_stats(const float* __restrict__ X,
                                                const int* __restrict__ labels,
                                                const int* __restrict__ slen,
                                                float* __restrict__ mu,
                                                float* __restrict__ cnt,
                                                unsigned int* __restrict__ wpbits)
{
  int b = blockIdx.x, t = threadIdx.x;
  int td = t & 255, sg = t >> 8;
  __shared__ int lab[S_];
  __shared__ float red[1024];
  __shared__ float part[4][256][4];
  int L = slen[b];
  if (t < S_) {
    int lb = labels[b*S_ + t];
    lab[t] = (t < L) ? lb : -1;
  }
  __syncthreads();
  if (t < 16) {
    unsigned int wword = 0;
    for (int i2 = 0; i2 < 32; i2++) if (lab[t*32 + i2] == 1) wword |= (1u << i2);
    wpbits[b*16 + t] = wword;
  }
  red[t] = (t < S_) ? ((lab[t]==1) ? 1.f : 0.f) : 0.f;
  __syncthreads();
  for (int o=512;o>0;o>>=1){ if(t<o) red[t]+=red[t+o]; __syncthreads(); }
  float cp = red[0]; __syncthreads();
  red[t] = (t < S_) ? ((lab[t]==0) ? 1.f : 0.f) : 0.f;
  __syncthreads();
  for (int o=512;o>0;o>>=1){ if(t<o) red[t]+=red[t+o]; __syncthreads(); }
  float cn = red[0];
  if (t==0){ cnt[b*2+0]=cn; cnt[b*2+1]=cp; }
  float sp0=0,sp1=0,sn0=0,sn1=0;
  const float* Xb = X + (size_t)b*S_*D_;
  for (int s=sg*128; s<sg*128+128; s++){
    int e = lab[s];
    if (e < 0) continue;
    float x0 = Xb[(size_t)s*D_ + td];
    float x1 = Xb[(size_t)s*D_ + td + 256];
    if (e==1){ sp0+=x0; sp1+=x1; } else { sn0+=x0; sn1+=x1; }
  }
  part[sg][td][0]=sn0; part[sg][td][1]=sn1; part[sg][td][2]=sp0; part[sg][td][3]=sp1;
  __syncthreads();
  if (sg == 0){
    float a0=0,a1=0,a2=0,a3=0;
    #pragma unroll
    for (int g=0;g<4;g++){ a0+=part[g][td][0]; a1+=part[g][td][1]; a2+=part[g][td][2]; a3+=part[g][td][3]; }
    float stv = (float)L;
    float* mb = mu + (size_t)b*3*D_;
    mb[0*D_ + td] = a0/cn;      mb[0*D_ + td+256] = a1/cn;
    mb[1*D_ + td] = a2/cp;      mb[1*D_ + td+256] = a3/cp;
    mb[2*D_ + td] = (a0+a2)/stv; mb[2*D_ + td+256] = (a1+a3)/stv;
  }
}

// ---------------- prep: transpose X -> f16 hi/lo [B][D][S], valid-masked ----------------
__global__ __launch_bounds__(TPB) void k_prep(const float* __restrict__ X,
                                              const int* __restrict__ slen,
                                              unsigned short* __restrict__ Xvh,
                                              unsigned short* __restrict__ Xvl)
{
  int b = blockIdx.y, z = blockIdx.x;
  int d0 = (z>>3)*64, s0 = (z&7)*64;
  int t = threadIdx.x;
  __shared__ float Tl[64][65];
  const float* src = X + ((size_t)b*S_ + s0)*D_ + d0;
  { int r = t>>2, seg = (t&3)*16;
    const float4* s4 = (const float4*)(src + (size_t)r*D_ + seg);
    #pragma unroll
    for (int i=0;i<4;i++){ float4 v = s4[i];
      Tl[seg+i*4+0][r]=v.x; Tl[seg+i*4+1][r]=v.y; Tl[seg+i*4+2][r]=v.z; Tl[seg+i*4+3][r]=v.w; } }
  __syncthreads();
  int L = slen[b];
  int dr = t>>2, sc = (t&3)*16;
  union U16 { unsigned short u[8]; uint4 v; };
  U16 H[2], Lo[2];
  #pragma unroll
  for (int g=0; g<2; g++)
    #pragma unroll
    for (int i=0;i<8;i++){
      int si = sc + g*8 + i;
      float x = (s0+si < L) ? Tl[dr][si] : 0.f;
      _Float16 hh = (_Float16)x;
      float lo = x - (float)hh;
      H[g].u[i]  = __builtin_bit_cast(unsigned short, hh);
      Lo[g].u[i] = __builtin_bit_cast(unsigned short, (_Float16)lo);
    }
  size_t o = ((size_t)b*D_ + d0+dr)*S_ + s0 + sc;
  *(uint4*)(Xvh+o)   = H[0].v;  *(uint4*)(Xvh+o+8) = H[1].v;
  *(uint4*)(Xvl+o)   = Lo[0].v; *(uint4*)(Xvl+o+8) = Lo[1].v;
}

// ---------------- MFMA Gram -> A matrices (upper 128-tiles incl. diagonal) ----------------
__global__ __launch_bounds__(TPB,2) void k_gram(const unsigned short* __restrict__ Xvh,
                                                const unsigned short* __restrict__ Xvl,
                                                const unsigned int* __restrict__ wpbits,
                                                const float* __restrict__ mu,
                                                const float* __restrict__ cnt,
                                                const int* __restrict__ slen,
                                                float* __restrict__ A)
{
  __shared__ unsigned short sAvh[128][32], sAvl[128][32], sAph[128][32], sApl[128][32],
                            sBvh[128][32], sBvl[128][32];
  int id = blockIdx.x;
  int g = id>>3;
  int b = (g/10)*8 + (id&7);
  int z = g%10;
  int ti=0; while (z >= 4-ti){ z -= 4-ti; ti++; } int tj = ti + z;
  int i0 = ti*128, j0 = tj*128;
  int t = threadIdx.x, lane = t&63, w = t>>6;
  int wr = w>>1, wc = w&1, l15 = lane&15;

  f32x4 acc_t[4][4], acc_p[4][4];
  f32x4 z4 = {0.f,0.f,0.f,0.f};
  #pragma unroll
  for (int mf=0;mf<4;mf++)
    #pragma unroll
    for (int nf=0;nf<4;nf++){ acc_t[mf][nf]=z4; acc_p[mf][nf]=z4; }

  const size_t baseA = ((size_t)b*D_ + i0)*S_;
  const size_t baseB = ((size_t)b*D_ + j0)*S_;
  int phx = (lane>>4) ^ ((l15>>1)&3);

  for (int ks=0; ks<16; ks++){
    int s0 = ks*32;
    unsigned int wpw = wpbits[b*16 + ks];
    __syncthreads();
    #pragma unroll
    for (int h=0; h<2; h++){
      int ci = t + h*256;
      int row = ci>>2, cpos = ci&3;
      int ph = cpos ^ ((row>>1)&3);
      size_t ga = baseA + (size_t)row*S_ + s0 + cpos*8;
      size_t gb = baseB + (size_t)row*S_ + s0 + cpos*8;
      uint4 vh = *(const uint4*)(Xvh+ga);
      uint4 vl = *(const uint4*)(Xvl+ga);
      uint4 bh = *(const uint4*)(Xvh+gb);
      uint4 bl = *(const uint4*)(Xvl+gb);
      unsigned int m8 = (wpw >> (cpos*8)) & 0xFFu;
      uint4 mk;
      mk.x = ((m8&1u)?0xFFFFu:0u)  | ((m8&2u)?0xFFFF0000u:0u);
      mk.y = ((m8&4u)?0xFFFFu:0u)  | ((m8&8u)?0xFFFF0000u:0u);
      mk.z = ((m8&16u)?0xFFFFu:0u) | ((m8&32u)?0xFFFF0000u:0u);
      mk.w = ((m8&64u)?0xFFFFu:0u) | ((m8&128u)?0xFFFF0000u:0u);
      uint4 p4, q4;
      p4.x = vh.x&mk.x; p4.y = vh.y&mk.y; p4.z = vh.z&mk.z; p4.w = vh.w&mk.w;
      q4.x = vl.x&mk.x; q4.y = vl.y&mk.y; q4.z = vl.z&mk.z; q4.w = vl.w&mk.w;
      *(uint4*)&sAvh[row][ph*8] = vh;
      *(uint4*)&sAvl[row][ph*8] = vl;
      *(uint4*)&sAph[row][ph*8] = p4;
      *(uint4*)&sApl[row][ph*8] = q4;
      *(uint4*)&sBvh[row][ph*8] = bh;
      *(uint4*)&sBvl[row][ph*8] = bl;
    }
    __syncthreads();
    f16x8 Avh[4], Avl[4], Aph[4], Apl[4];
    #pragma unroll
    for (int mf=0;mf<4;mf++){
      int r = wr*64 + mf*16 + l15;
      Avh[mf] = __builtin_bit_cast(f16x8, *(const uint4*)&sAvh[r][phx*8]);
      Avl[mf] = __builtin_bit_cast(f16x8, *(const uint4*)&sAvl[r][phx*8]);
      Aph[mf] = __builtin_bit_cast(f16x8, *(const uint4*)&sAph[r][phx*8]);
      Apl[mf] = __builtin_bit_cast(f16x8, *(const uint4*)&sApl[r][phx*8]);
    }
    #pragma unroll
    for (int nf=0;nf<4;nf++){
      int r = wc*64 + nf*16 + l15;
      f16x8 Bh = __builtin_bit_cast(f16x8, *(const uint4*)&sBvh[r][phx*8]);
      f16x8 Bl = __builtin_bit_cast(f16x8, *(const uint4*)&sBvl[r][phx*8]);
      #pragma unroll
      for (int mf=0;mf<4;mf++){
        acc_t[mf][nf] = __builtin_amdgcn_mfma_f32_16x16x32_f16(Avh[mf], Bh, acc_t[mf][nf],0,0,0);
        acc_t[mf][nf] = __builtin_amdgcn_mfma_f32_16x16x32_f16(Avh[mf], Bl, acc_t[mf][nf],0,0,0);
        acc_t[mf][nf] = __builtin_amdgcn_mfma_f32_16x16x32_f16(Avl[mf], Bh, acc_t[mf][nf],0,0,0);
        acc_p[mf][nf] = __builtin_amdgcn_mfma_f32_16x16x32_f16(Aph[mf], Bh, acc_p[mf][nf],0,0,0);
        acc_p[mf][nf] = __builtin_amdgcn_mfma_f32_16x16x32_f16(Aph[mf], Bl, acc_p[mf][nf],0,0,0);
        acc_p[mf][nf] = __builtin_amdgcn_mfma_f32_16x16x32_f16(Apl[mf], Bh, acc_p[mf][nf],0,0,0);
      }
    }
  }
  float cn = cnt[b*2+0], cp = cnt[b*2+1];
  float stv = (float)slen[b];
  float kn = 0.1f/(cn-1.f), kp = 0.1f/(cp-1.f), kt = 0.9f/(stv-1.f);
  float rn = 0.1f*cn/(cn-1.f), rp = 0.1f*cp/(cp-1.f), rt = 0.9f*stv/(stv-1.f);
  const float* mb = mu + (size_t)b*3*D_;
  float* A0 = A + (size_t)(b*2+0)*D_*D_;
  float* A1 = A + (size_t)(b*2+1)*D_*D_;
  int rbase = i0 + wr*64 + (lane>>4)*4;
  int cbase = j0 + wc*64 + l15;
  #pragma unroll
  for (int mf=0;mf<4;mf++){
    #pragma unroll
    for (int i=0;i<4;i++){
      int r = rbase + mf*16 + i;
      float mnr = mb[r], mpr = mb[D_+r], mtr = mb[2*D_+r];
      #pragma unroll
      for (int nf=0;nf<4;nf++){
        int c = cbase + nf*16;
        float mnc = mb[c], mpc = mb[D_+c], mtc = mb[2*D_+c];
        float gp = acc_p[mf][nf][i];
        float gt = acc_t[mf][nf][i];
        float gn = gt - gp;
        float diag = (r==c)?0.1f:0.f;
        A0[(size_t)r*D_ + c] = kn*gn + kt*gt - rn*mnr*mnc - rt*mtr*mtc + diag;
        A1[(size_t)r*D_ + c] = kp*gp + kt*gt - rp*mpr*mpc - rt*mtr*mtc + diag;
      }
    }
  }
}

// ---------------- diag block Cholesky + triangular inverse (transposed out) ----------------
__global__ __launch_bounds__(TPB) void k_diag(float* __restrict__ A,
                                              float* __restrict__ invDT, int j)
{
  int m, t0; decode_mt(blockIdx.x, 1, m, t0); (void)t0;
  int t = threadIdx.x;
  __shared__ float Ld[64][65];
  __shared__ float Iv[64][65];
  float* Ab = A + (size_t)m*D_*D_ + (size_t)(j*NB)*D_ + j*NB;
  for (int l=t; l<4096; l+=TPB){ int r=l>>6, c=l&63; Ld[r][c] = Ab[(size_t)r*D_ + c]; Iv[r][c] = 0.f; }
  __syncthreads();
  for (int k=0;k<64;k++){
    if (t==0) Ld[k][k] = sqrtf(Ld[k][k]);
    __syncthreads();
    if (t>k && t<64) Ld[t][k] /= Ld[k][k];
    __syncthreads();
    for (int l=t; l<4096; l+=TPB){
      int r=l>>6, c=l&63;
      if (r>k && c>k) Ld[r][c] = fmaf(-Ld[r][k], Ld[c][k], Ld[r][c]);
    }
    __syncthreads();
  }
  if (t < 64){
    int c = t;
    Iv[c][c] = 1.f/Ld[c][c];
    for (int r=c+1;r<64;r++){
      float s = 0.f;
      for (int k2=c;k2<r;k2++) s += Ld[r][k2]*Iv[k2][c];
      Iv[r][c] = -s/Ld[r][r];
    }
  }
  __syncthreads();
  float* Ib = invDT + ((size_t)m*8 + j)*4096;
  for (int l=t; l<4096; l+=TPB){ Ib[l] = Iv[l&63][l>>6]; }
}

// ---------------- panel: upper(j,ib) <- invD * upper(j,ib); emit f16T hi/lo ----------------
__global__ __launch_bounds__(TPB) void k_panel(float* __restrict__ A,
                                               const float* __restrict__ invDT,
                                               unsigned short* __restrict__ Ut,
                                               int j, int W)
{
  int m, ti; decode_mt(blockIdx.x, W, m, ti);
  int ib = j + 1 + ti;
  int t = threadIdx.x, tr = t&15, tc = t>>4;
  __shared__ float Ta[64][68], Tb[64][68];
  float* U = A + (size_t)m*D_*D_ + (size_t)(j*NB)*D_ + ib*NB;
  stage_D(invDT + ((size_t)m*8 + j)*4096, 64, Ta, t);
  stage_D(U, D_, Tb, t);
  __syncthreads();
  float acc[4][4] = {};
  mm_acc68(Ta, Tb, acc, tr, tc);
  #pragma unroll
  for (int u=0;u<4;u++){
    float4 o = make_float4(acc[u][0],acc[u][1],acc[u][2],acc[u][3]);
    *((float4*)(U + (size_t)(tr*4+u)*D_ + tc*4)) = o;
  }
  // emit f16 hi/lo transposed [row y][k x] for MFMA trail
  __syncthreads();
  unsigned short* shh = (unsigned short*)Ta;
  unsigned short* shl = (unsigned short*)Tb;
  #pragma unroll
  for (int u=0;u<4;u++)
    #pragma unroll
    for (int v=0;v<4;v++){
      float val = acc[u][v];                  // P[x=tr*4+u][y=tc*4+v]
      _Float16 h = (_Float16)val;
      float lo = val - (float)h;
      shh[(tc*4+v)*72 + tr*4+u] = __builtin_bit_cast(unsigned short, h);
      shl[(tc*4+v)*72 + tr*4+u] = __builtin_bit_cast(unsigned short, (_Float16)lo);
    }
  __syncthreads();
  unsigned short* Ub = Ut + ((size_t)m*28 + pidx(j, ib)) * 8192;
  { int r = t>>2, cs = (t&3)*16;
    *(uint4*)(Ub + r*64 + cs)          = *(uint4*)&shh[r*72 + cs];
    *(uint4*)(Ub + r*64 + cs + 8)      = *(uint4*)&shh[r*72 + cs + 8];
    *(uint4*)(Ub + 4096 + r*64 + cs)   = *(uint4*)&shl[r*72 + cs];
    *(uint4*)(Ub + 4096 + r*64 + cs+8) = *(uint4*)&shl[r*72 + cs + 8];
  }
}

// ---------------- MFMA trail core: acc += Ua^T Ub over one K-64 col ----------------
__device__ __forceinline__ void trail_stage(const unsigned short* __restrict__ Ua,
                                            const unsigned short* __restrict__ Ub,
                                            unsigned short (*Ah)[72], unsigned short (*Al)[72],
                                            unsigned short (*Bh)[72], unsigned short (*Bl)[72],
                                            int t)
{
  int r = t>>2, cs = (t&3)*16;
  *(uint4*)&Ah[r][cs]   = *(const uint4*)(Ua + r*64 + cs);
  *(uint4*)&Ah[r][cs+8] = *(const uint4*)(Ua + r*64 + cs + 8);
  *(uint4*)&Al[r][cs]   = *(const uint4*)(Ua + 4096 + r*64 + cs);
  *(uint4*)&Al[r][cs+8] = *(const uint4*)(Ua + 4096 + r*64 + cs + 8);
  *(uint4*)&Bh[r][cs]   = *(const uint4*)(Ub + r*64 + cs);
  *(uint4*)&Bh[r][cs+8] = *(const uint4*)(Ub + r*64 + cs + 8);
  *(uint4*)&Bl[r][cs]   = *(const uint4*)(Ub + 4096 + r*64 + cs);
  *(uint4*)&Bl[r][cs+8] = *(const uint4*)(Ub + 4096 + r*64 + cs + 8);
}

__device__ __forceinline__ void trail_mfma(const unsigned short (*Ah)[72], const unsigned short (*Al)[72],
                                           const unsigned short (*Bh)[72], const unsigned short (*Bl)[72],
                                           f32x4 acc[4], int w, int l15, int lk)
{
  #pragma unroll
  for (int s=0;s<2;s++){
    f16x8 Afh = __builtin_bit_cast(f16x8, *(const uint4*)&Ah[w*16 + l15][s*32 + lk*8]);
    f16x8 Afl = __builtin_bit_cast(f16x8, *(const uint4*)&Al[w*16 + l15][s*32 + lk*8]);
    #pragma unroll
    for (int ni=0;ni<4;ni++){
      f16x8 Bfh = __builtin_bit_cast(f16x8, *(const uint4*)&Bh[ni*16 + l15][s*32 + lk*8]);
      f16x8 Bfl = __builtin_bit_cast(f16x8, *(const uint4*)&Bl[ni*16 + l15][s*32 + lk*8]);
      acc[ni] = __builtin_amdgcn_mfma_f32_16x16x32_f16(Afh, Bfh, acc[ni],0,0,0);
      acc[ni] = __builtin_amdgcn_mfma_f32_16x16x32_f16(Afh, Bfl, acc[ni],0,0,0);
      acc[ni] = __builtin_amdgcn_mfma_f32_16x16x32_f16(Afl, Bfh, acc[ni],0,0,0);
    }
  }
}

__device__ __forceinline__ void trail_rmw(float* __restrict__ Cb, const f32x4 acc[4],
                                          int w, int l15, int lk)
{
  #pragma unroll
  for (int ni=0;ni<4;ni++)
    #pragma unroll
    for (int i=0;i<4;i++){
      int r = w*16 + lk*4 + i, cc = ni*16 + l15;
      float* pC = Cb + (size_t)r*D_ + cc;
      *pC -= acc[ni][i];
    }
}

// ---------------- trailrow (MFMA): upper(row,b) -= U(j,row)^T U(j,b) ----------------
__global__ __launch_bounds__(TPB) void k_trailrow(float* __restrict__ A,
                                                  const unsigned short* __restrict__ Ut,
                                                  int j, int row, int W)
{
  int m, z; decode_mt(blockIdx.x, W, m, z);
  int b2 = row + z;
  int t = threadIdx.x, lane = t&63, w = t>>6, l15 = lane&15, lk = lane>>4;
  __shared__ unsigned short Ah[64][72], Al[64][72], Bh[64][72], Bl[64][72];
  const unsigned short* Um = Ut + (size_t)m*28*8192;
  trail_stage(Um + (size_t)pidx(j,row)*8192, Um + (size_t)pidx(j,b2)*8192, Ah, Al, Bh, Bl, t);
  __syncthreads();
  f32x4 acc[4];
  #pragma unroll
  for (int ni=0;ni<4;ni++) acc[ni] = (f32x4){0.f,0.f,0.f,0.f};
  trail_mfma(Ah, Al, Bh, Bl, acc, w, l15, lk);
  float* Cb = A + (size_t)m*D_*D_ + (size_t)(row*NB)*D_ + b2*NB;
  trail_rmw(Cb, acc, w, l15, lk);
}

// ---------------- trail2 (MFMA): upper(a,b) -= sum over cols jb, jb+1 ----------------
__global__ __launch_bounds__(TPB) void k_trail2(float* __restrict__ A,
                                                const unsigned short* __restrict__ Ut,
                                                int jb, int W)
{
  int m, z; decode_mt(blockIdx.x, W, m, z);
  int base = jb + 2;
  int Tn = NT - base;
  int p = 0, zz = z;
  while (zz >= Tn - p){ zz -= Tn - p; p++; }
  int a2 = base + p, b2 = a2 + zz;
  int t = threadIdx.x, lane = t&63, w = t>>6, l15 = lane&15, lk = lane>>4;
  __shared__ unsigned short Ah[64][72], Al[64][72], Bh[64][72], Bl[64][72];
  const unsigned short* Um = Ut + (size_t)m*28*8192;
  f32x4 acc[4];
  #pragma unroll
  for (int ni=0;ni<4;ni++) acc[ni] = (f32x4){0.f,0.f,0.f,0.f};
  #pragma unroll
  for (int c=0;c<2;c++){
    int j = jb + c;
    __syncthreads();
    trail_stage(Um + (size_t)pidx(j,a2)*8192, Um + (size_t)pidx(j,b2)*8192, Ah, Al, Bh, Bl, t);
    __syncthreads();
    trail_mfma(Ah, Al, Bh, Bl, acc, w, l15, lk);
  }
  float* Cb = A + (size_t)m*D_*D_ + (size_t)(a2*NB)*D_ + b2*NB;
  trail_rmw(Cb, acc, w, l15, lk);
}

// ---------------- fused rform + forward solve + maha + logits ----------------
__global__ __launch_bounds__(TPB) void k_solvefin(const float* __restrict__ Qs,
                                                  const float* __restrict__ mu,
                                                  const float* __restrict__ A,
                                                  const float* __restrict__ invDT,
                                                  float* __restrict__ Z,
                                                  const int* __restrict__ qlen,
                                                  const float* __restrict__ lps,
                                                  float* __restrict__ out)
{
  int m, t0; decode_mt(blockIdx.x, 4, m, t0);
  int q0 = t0*NB;
  int b = m>>1, cls = m&1;
  int t = threadIdx.x, tr = t&15, tc = t>>4;
  __shared__ float Ta[64][68], Tb[64][68];
  const float* Am = A + (size_t)m*D_*D_;
  float* Zm = Z + (size_t)m*D_*Q_;
  const float* muv = mu + ((size_t)b*3 + cls)*D_;
  float cs[4] = {0.f,0.f,0.f,0.f};
  for (int j=0;j<NT;j++){
    float acc[4][4];
    {
      float4 mv = *(const float4*)&muv[j*NB + tr*4];
      #pragma unroll
      for (int v=0;v<4;v++){
        float4 qv = *(const float4*)&Qs[((size_t)b*Q_ + q0 + tc*4 + v)*D_ + j*NB + tr*4];
        acc[0][v] = mv.x - qv.x;
        acc[1][v] = mv.y - qv.y;
        acc[2][v] = mv.z - qv.z;
        acc[3][v] = mv.w - qv.w;
      }
    }
    for (int k=0;k<j;k++){
      stage_D(Am + (size_t)(k*NB)*D_ + j*NB, D_, Ta, t);
      { int r = t >> 2, seg = (t & 3)*16;
        const float4* s4 = (const float4*)(Zm + (size_t)(k*NB + r)*Q_ + q0 + seg);
        #pragma unroll
        for (int i=0;i<4;i++) *((float4*)&Tb[r][seg + i*4]) = s4[i];
      }
      __syncthreads();
      for (int kk=0;kk<64;kk++){
        float4 av = *((const float4*)&Ta[kk][tr*4]);
        float4 bv = *((const float4*)&Tb[kk][tc*4]);
        float a[4]={av.x,av.y,av.z,av.w}, bb2[4]={bv.x,bv.y,bv.z,bv.w};
        #pragma unroll
        for (int u=0;u<4;u++)
          #pragma unroll
          for (int v=0;v<4;v++) acc[u][v] = fmaf(-a[u], bb2[v], acc[u][v]);
      }
      __syncthreads();
    }
    #pragma unroll
    for (int u=0;u<4;u++)
      #pragma unroll
      for (int v=0;v<4;v++) Tb[tr*4+u][tc*4+v] = acc[u][v];
    stage_D(invDT + ((size_t)m*8 + j)*4096, 64, Ta, t);
    __syncthreads();
    float o4[4][4] = {};
    for (int kk=0;kk<64;kk++){
      float4 av = *((const float4*)&Ta[kk][tr*4]);
      float4 bv = *((const float4*)&Tb[kk][tc*4]);
      float a[4]={av.x,av.y,av.z,av.w}, bb2[4]={bv.x,bv.y,bv.z,bv.w};
      #pragma unroll
      for (int u=0;u<4;u++)
        #pragma unroll
        for (int v=0;v<4;v++) o4[u][v] = fmaf(a[u], bb2[v], o4[u][v]);
    }
    if (j < NT-1){
      #pragma unroll
      for (int u=0;u<4;u++){
        float4 o = make_float4(o4[u][0], o4[u][1], o4[u][2], o4[u][3]);
        *((float4*)(Zm + (size_t)(j*NB + tr*4+u)*Q_ + q0 + tc*4)) = o;
      }
    }
    #pragma unroll
    for (int u=0;u<4;u++)
      #pragma unroll
      for (int v=0;v<4;v++) cs[v] = fmaf(o4[u][v], o4[u][v], cs[v]);
    __syncthreads();
  }
  float* red = &Ta[0][0];
  #pragma unroll
  for (int v=0;v<4;v++) red[(tc*4+v)*16 + tr] = cs[v];
  __syncthreads();
  if (t < 64){
    float s = 0.f;
    #pragma unroll
    for (int i=0;i<16;i++) s += red[t*16 + i];
    int q = q0 + t;
    float valid = (q < qlen[b]) ? 1.f : 0.f;
    float s2 = expf(2.f*lps[0]);
    out[((size_t)b*Q_ + q)*2 + cls] = -s2*s*valid;
  }
}

extern "C" void kernel_launch(void* const* d_in, const int* in_sizes, int n_in,
                              void* d_out, int out_size, void* d_ws, size_t ws_size,
                              hipStream_t stream) {
  (void)in_sizes; (void)n_in; (void)out_size;
  const float* X   = (const float*)d_in[0];
  const int*   lab = (const int*)d_in[1];
  const float* Qs  = (const float*)d_in[2];
  const int*   sl  = (const int*)d_in[3];
  const int*   ql  = (const int*)d_in[4];
  const float* lps = (const float*)d_in[5];
  float* out = (float*)d_out;

  float* A  = (float*)d_ws;                          // [512,512,512] f32
  float* Z  = A + (size_t)NM_*D_*D_;                 // [512,512,256] f32
  unsigned short* Xvh = (unsigned short*)Z;          // overlays Z (gram phase only)
  unsigned short* Xvl = Xvh + (size_t)B_*D_*S_;
  unsigned short* Ut  = (unsigned short*)Z;          // overlays Z (chol phase only): [512][28][8192]
  float* invDT = Z + (size_t)NM_*D_*Q_;              // [512,8,64,64] f32 (transposed)
  float* mu   = invDT + (size_t)NM_*8*64*64;         // [256,3,512]
  float* cnt  = mu + (size_t)B_*3*D_;                // [256,2]
  unsigned int* wpbits = (unsigned int*)(cnt + B_*2);// [256,16]
  size_t need = (size_t)((char*)(wpbits + B_*16) - (char*)d_ws);
  if (ws_size < need) return;

  k_stats<<<dim3(B_), dim3(1024), 0, stream>>>(X, lab, sl, mu, cnt, wpbits);
  k_prep<<<dim3(64, B_), dim3(TPB), 0, stream>>>(X, sl, Xvh, Xvl);
  k_gram<<<dim3(2560), dim3(TPB), 0, stream>>>(Xvh, Xvl, wpbits, mu, cnt, sl, A);

  // lazy two-column Cholesky with MFMA trail (f16T panels live in the Z region)
  for (int j=0; j<NT; j+=2){
    k_diag<<<dim3(NM_), dim3(TPB), 0, stream>>>(A, invDT, j);
    int nb0 = NT-1-j;
    if (nb0 > 0){
      k_panel<<<dim3(NM_*nb0), dim3(TPB), 0, stream>>>(A, invDT, Ut, j, nb0);
      int wr = NT - (j+1);
      k_trailrow<<<dim3(NM_*wr), dim3(TPB), 0, stream>>>(A, Ut, j, j+1, wr);
      k_diag<<<dim3(NM_), dim3(TPB), 0, stream>>>(A, invDT, j+1);
      int nb1 = NT-1-(j+1);
      if (nb1 > 0){
        k_panel<<<dim3(NM_*nb1), dim3(TPB), 0, stream>>>(A, invDT, Ut, j+1, nb1);
        int Tn = NT - (j+2);
        int np = Tn*(Tn+1)/2;
        if (np > 0) k_trail2<<<dim3(NM_*np), dim3(TPB), 0, stream>>>(A, Ut, j, np);
      }
    }
  }

  k_solvefin<<<dim3(NM_*4), dim3(TPB), 0, stream>>>(Qs, mu, A, invDT, Z, ql, lps, out);
}